// Round 10
// baseline (607.787 us; speedup 1.0000x reference)
//
#include <hip/hip_runtime.h>
#include <hip/hip_bf16.h>

typedef __attribute__((ext_vector_type(4))) float f32x4;
typedef __attribute__((ext_vector_type(8))) short s16x8;
typedef __attribute__((ext_vector_type(4))) float f4v;
typedef __attribute__((ext_vector_type(4))) unsigned short us4;
typedef unsigned short u16;
typedef unsigned int u32;

#define H_ 12
#define NTOK 4096
#define DHEAD 64
#define MFEAT 256
#define CDIM 768

#define NORMALIZER 0.35355339059327373f  /* 64^-0.25 */
#define DIAGSCALE 0.0625f                /* 0.5 * NORMALIZER^2 */
#define RATIO_ 0.0625f                   /* 256^-0.5 */
#define EPS_ 1e-4f

#define MFMA(a, b, c) __builtin_amdgcn_mfma_f32_16x16x32_bf16((a), (b), (c), 0, 0, 0)

__device__ __forceinline__ float bf2f(u16 u) {
  union { float f; u32 v; } x; x.v = ((u32)u) << 16; return x.f;
}
__device__ __forceinline__ u16 f2bf(float f) {
  union { float f; u32 v; } x; x.f = f;
  u32 v = x.v + 0x7FFFu + ((x.v >> 16) & 1u);
  return (u16)(v >> 16);
}
__device__ __forceinline__ u32 fenc(float f) {
  u32 u = __float_as_uint(f);
  return (u & 0x80000000u) ? ~u : (u | 0x80000000u);
}
__device__ __forceinline__ float fdec(u32 k) {
  u32 u = (k & 0x80000000u) ? (k & 0x7fffffffu) : ~k;
  return __uint_as_float(u);
}
__device__ __forceinline__ void glds16(const u16* g, u16* l) {
  __builtin_amdgcn_global_load_lds((const __attribute__((address_space(1))) void*)g,
                                   (__attribute__((address_space(3))) void*)l, 16, 0, 0);
}

// write a wave's staged 64x64 bf16 tile (rows padded to 72) to dst
__device__ __forceinline__ void st_write64(const u16* stw, u16* dst, long ld, int lane) {
  int r0 = lane >> 3, cc = lane & 7;
#pragma unroll
  for (int c = 0; c < 8; ++c) {
    int row = c * 8 + r0;
    s16x8 v = *(const s16x8*)(stw + row * 72 + cc * 8);
    *(s16x8*)(dst + (long)row * ld + cc * 8) = v;
  }
}

// ---------------- fused init + fp32->bf16 converts (block-aligned segments) ----------------
__global__ void cvt_all(const float* __restrict__ x, const float* __restrict__ wq,
                        const float* __restrict__ wp, const float* __restrict__ pj,
                        u16* __restrict__ xb, u16* __restrict__ wqb,
                        u16* __restrict__ wpb, u16* __restrict__ pjb, u32* __restrict__ mk) {
  int b = blockIdx.x;
  if (b == 0 && threadIdx.x < 8) mk[threadIdx.x] = 0u;
  const float* s;
  u16* d;
  int base;
  if (b < 24576)      { s = x;  d = xb;  base = b; }
  else if (b < 26304) { s = wq; d = wqb; base = b - 24576; }
  else if (b < 26880) { s = wp; d = wpb; base = b - 26304; }
  else                { s = pj; d = pjb; base = b - 26880; }
  long i = (long)base * 256 + threadIdx.x;
  f4v v = *(const f4v*)(s + i * 4);
  us4 o;
#pragma unroll
  for (int j = 0; j < 4; ++j) o[j] = f2bf(v[j]);
  *(us4*)(d + i * 4) = o;
}

// ---------------- K0: QKV GEMM, 128x256 tile, per-wave 64x128 (4x8 frags), BK=64 ----------------
// grid (9,256); XCD-concentrated: group of 9 N-panel blocks share one A-panel on one XCD.
__global__ __launch_bounds__(256) void k0_qkv(const u16* __restrict__ A, const u16* __restrict__ Bm,
                                              u16* __restrict__ qb, u16* __restrict__ kb,
                                              u16* __restrict__ vT) {
  __shared__ u16 smem[24576];   // lA[0,8192) lB[8192,24576); epilogue: 4x4608 stage alias
  u16* lA = smem;
  u16* lB = smem + 8192;
  int tid = threadIdx.x, lane = tid & 63, wid = tid >> 6;
  // XCD-concentration remap (bijective on [0,2304))
  int p = blockIdx.x + blockIdx.y * 9;
  int r8 = p & 7, q = p >> 3;        // q in [0,288)
  int bx = q % 9;                    // N-panel member
  int by = (q / 9) * 8 + r8;         // M-panel (same XCD for all 9 members)
  int m0 = by << 7, n0 = bx << 8;
  int wr = (wid >> 1) << 6;          // {0,64}
  int wc = (wid & 1) << 7;           // {0,128}
  int l15 = lane & 15, lk = lane >> 4;
  int lr = lane >> 3;            // row within 8-row staging group
  int lu = (lane & 7) ^ lr;      // pre-swizzled source 16B-unit: lds[r][u]=glob[r][u^(r&7)]
  const u16* Ab = A + (long)m0 * CDIM;
  const u16* Bb = Bm + (long)n0 * CDIM;
  const u16* gA = Ab + (long)(wid * 32 + lr) * CDIM + lu * 8;
  const u16* gB = Bb + (long)(wid * 64 + lr) * CDIM + lu * 8;
  u16* dA = lA + wid * 2048;
  u16* dB = lB + wid * 4096;
  f32x4 acc[4][8];
#pragma unroll
  for (int i = 0; i < 4; ++i)
#pragma unroll
    for (int j = 0; j < 8; ++j) acc[i][j] = (f32x4){0.f, 0.f, 0.f, 0.f};
  for (int k0 = 0; k0 < CDIM; k0 += 64) {
    __syncthreads();
#pragma unroll
    for (int g = 0; g < 4; ++g)
      glds16(gA + k0 + (long)g * 8 * CDIM, dA + g * 512);
#pragma unroll
    for (int g = 0; g < 8; ++g)
      glds16(gB + k0 + (long)g * 8 * CDIM, dB + g * 512);
    __syncthreads();
#pragma unroll
    for (int ks = 0; ks < 2; ++ks) {
      s16x8 af[4], bv[8];
      int co = ((ks * 4 + lk) ^ (l15 & 7)) * 8;   // swizzled read unit
#pragma unroll
      for (int i = 0; i < 4; ++i)
        af[i] = *(const s16x8*)(lA + (wr + i * 16 + l15) * 64 + co);
#pragma unroll
      for (int j = 0; j < 8; ++j)
        bv[j] = *(const s16x8*)(lB + (wc + j * 16 + l15) * 64 + co);
#pragma unroll
      for (int i = 0; i < 4; ++i)
#pragma unroll
        for (int j = 0; j < 8; ++j) acc[i][j] = MFMA(af[i], bv[j], acc[i][j]);
    }
  }
  __syncthreads();  // before reusing smem as epilogue stage
  int rowbase = m0 + wr;
  int b = rowbase >> 12;
  int nloc = rowbase & (NTOK - 1);
  u16* stw = smem + wid * 4608;
#pragma unroll
  for (int jh = 0; jh < 2; ++jh) {  // two 64-col halves of the wave's 128-col output
    int colbase = n0 + wc + jh * 64;
    int qi = colbase / CDIM;
    int h = (colbase % CDIM) >> 6;
    if (qi < 2) {
#pragma unroll
      for (int i = 0; i < 4; ++i)
#pragma unroll
        for (int j4 = 0; j4 < 4; ++j4)
#pragma unroll
          for (int r = 0; r < 4; ++r)
            stw[(i * 16 + lk * 4 + r) * 72 + j4 * 16 + l15] = f2bf(acc[i][jh * 4 + j4][r]);
      u16* dst = (qi == 0 ? qb : kb) + ((long)(b * H_ + h) * NTOK + nloc) * DHEAD;
      st_write64(stw, dst, DHEAD, lane);
    } else {
      // transposed stage: st[dd][tok] (pack 4 r's into one b64)
#pragma unroll
      for (int i = 0; i < 4; ++i)
#pragma unroll
        for (int j4 = 0; j4 < 4; ++j4) {
          us4 w;
#pragma unroll
          for (int r = 0; r < 4; ++r) w[r] = f2bf(acc[i][jh * 4 + j4][r]);
          *(us4*)(stw + (j4 * 16 + l15) * 72 + i * 16 + lk * 4) = w;
        }
      u16* dst = vT + (long)(b * H_ + h) * DHEAD * NTOK + nloc;
      st_write64(stw, dst, NTOK, lane);
    }
    asm volatile("" ::: "memory");  // wave-local stw reuse (per-wave LDS ops are in-order)
  }
}

// ---------------- K2k pass1: global max of k_dash per batch ----------------
__global__ __launch_bounds__(256) void k2_k1(const u16* __restrict__ kb, const u16* __restrict__ projb,
                                             u32* __restrict__ mk) {
  __shared__ float wmax[4];
  int bh = blockIdx.y;
  int n0 = blockIdx.x << 6;
  const u16* Aq = kb + ((long)bh * NTOK + n0) * DHEAD;
  int tid = threadIdx.x, lane = tid & 63, wid = tid >> 6;
  int wc = wid << 6;
  int l15 = lane & 15, lk = lane >> 4;
  f32x4 acc[4][4];
#pragma unroll
  for (int i = 0; i < 4; ++i)
#pragma unroll
    for (int j = 0; j < 4; ++j) acc[i][j] = (f32x4){0.f, 0.f, 0.f, 0.f};
#pragma unroll
  for (int ks = 0; ks < 2; ++ks) {
    s16x8 a[4], bv[4];
#pragma unroll
    for (int i = 0; i < 4; ++i)
      a[i] = *(const s16x8*)(Aq + (long)(i * 16 + l15) * DHEAD + ks * 32 + lk * 8);
#pragma unroll
    for (int j = 0; j < 4; ++j)
      bv[j] = *(const s16x8*)(projb + (long)(wc + j * 16 + l15) * DHEAD + ks * 32 + lk * 8);
#pragma unroll
    for (int i = 0; i < 4; ++i)
#pragma unroll
      for (int j = 0; j < 4; ++j) acc[i][j] = MFMA(a[i], bv[j], acc[i][j]);
  }
  float m = -3.4e38f;
#pragma unroll
  for (int i = 0; i < 4; ++i)
#pragma unroll
    for (int j = 0; j < 4; ++j)
#pragma unroll
      for (int r = 0; r < 4; ++r) m = fmaxf(m, acc[i][j][r]);
  m = fmaxf(m, __shfl_xor(m, 1));
  m = fmaxf(m, __shfl_xor(m, 2));
  m = fmaxf(m, __shfl_xor(m, 4));
  m = fmaxf(m, __shfl_xor(m, 8));
  m = fmaxf(m, __shfl_xor(m, 16));
  m = fmaxf(m, __shfl_xor(m, 32));
  if (lane == 0) wmax[wid] = m;
  __syncthreads();
  if (tid == 0) {
    float mm = fmaxf(fmaxf(wmax[0], wmax[1]), fmaxf(wmax[2], wmax[3])) * NORMALIZER;
    atomicMax(mk + (blockIdx.y / H_), fenc(mm));
  }
}

// ---------------- K3f: fused phi(k) + context = k'^T @ v (512-token chunk, barrier-free) ----------------
// ctx8 layout: [nc][bh][dd][m]  (dd-major, coalesced for k3b)
__global__ __launch_bounds__(256) void k3f(const u16* __restrict__ kb, const u16* __restrict__ vT,
                                           const u16* __restrict__ projb, const u32* __restrict__ mk,
                                           float* __restrict__ ctx8, float* __restrict__ kpart) {
  __shared__ u16 smem[4 * 64 * 72];
  int bh = blockIdx.y, nc = blockIdx.x;  // nc in [0,8)
  int tid = threadIdx.x, lane = tid & 63, wid = tid >> 6;
  int l15 = lane & 15, lk = lane >> 4;
  int wc = wid << 6;
  float mg = fdec(mk[bh / H_]);
  const u16* Kb = kb + ((long)bh * NTOK + nc * 512) * DHEAD;
  const u16* Vb = vT + (long)bh * DHEAD * NTOK + nc * 512;
  u16* ktw = smem + wid * 4608;  // per-wave 9216B tile (wave-local!)
  f32x4 ctxa[4][4];
#pragma unroll
  for (int i = 0; i < 4; ++i)
#pragma unroll
    for (int j = 0; j < 4; ++j) ctxa[i][j] = (f32x4){0.f, 0.f, 0.f, 0.f};
  float cs[4] = {0.f, 0.f, 0.f, 0.f};
  for (int sb = 0; sb < 8; ++sb) {
    const u16* Ksb = Kb + sb * 64 * DHEAD;
    s16x8 a[4][2];
    float ss[4] = {0.f, 0.f, 0.f, 0.f};
#pragma unroll
    for (int i = 0; i < 4; ++i)
#pragma unroll
      for (int ks = 0; ks < 2; ++ks) {
        a[i][ks] = *(const s16x8*)(Ksb + (long)(i * 16 + l15) * DHEAD + ks * 32 + lk * 8);
#pragma unroll
        for (int e = 0; e < 8; ++e) { float f = bf2f((u16)a[i][ks][e]); ss[i] += f * f; }
      }
    float dgv[4];
#pragma unroll
    for (int i = 0; i < 4; ++i) {
      float s = ss[i];
      s += __shfl_xor(s, 16);
      s += __shfl_xor(s, 32);
      dgv[i] = s * DIAGSCALE;  // diag of token 16i+l15 (uniform over lk)
    }
    f32x4 dacc[4][4];
#pragma unroll
    for (int i = 0; i < 4; ++i)
#pragma unroll
      for (int j = 0; j < 4; ++j) dacc[i][j] = (f32x4){0.f, 0.f, 0.f, 0.f};
#pragma unroll
    for (int ks = 0; ks < 2; ++ks)
#pragma unroll
      for (int j = 0; j < 4; ++j) {
        s16x8 pb = *(const s16x8*)(projb + (long)(wc + j * 16 + l15) * DHEAD + ks * 32 + lk * 8);
#pragma unroll
        for (int i = 0; i < 4; ++i) dacc[i][j] = MFMA(a[i][ks], pb, dacc[i][j]);
      }
    // diag at token 16i+4lk+r via shuffle
    float dgr[4][4];
#pragma unroll
    for (int i = 0; i < 4; ++i)
#pragma unroll
      for (int r = 0; r < 4; ++r) dgr[i][r] = __shfl(dgv[i], 4 * lk + r);
    // phi -> kT (wave-local), packed b64 writes
#pragma unroll
    for (int i = 0; i < 4; ++i)
#pragma unroll
      for (int j = 0; j < 4; ++j) {
        us4 w;
#pragma unroll
        for (int r = 0; r < 4; ++r) {
          float v = RATIO_ * (__expf(dacc[i][j][r] * NORMALIZER - dgr[i][r] - mg) + EPS_);
          cs[j] += v;
          w[r] = f2bf(v);
        }
        *(us4*)(ktw + (j * 16 + l15) * 72 + i * 16 + lk * 4) = w;
      }
    // context MFMA: A = k'(features) rows from ktw, B = vT rows
#pragma unroll
    for (int ks = 0; ks < 2; ++ks) {
      s16x8 a2f[4], vb[4];
#pragma unroll
      for (int ii = 0; ii < 4; ++ii)
        a2f[ii] = *(const s16x8*)(ktw + (ii * 16 + l15) * 72 + ks * 32 + lk * 8);
#pragma unroll
      for (int jv = 0; jv < 4; ++jv)
        vb[jv] = *(const s16x8*)(Vb + (long)(jv * 16 + l15) * NTOK + sb * 64 + ks * 32 + lk * 8);
#pragma unroll
      for (int ii = 0; ii < 4; ++ii)
#pragma unroll
        for (int jv = 0; jv < 4; ++jv) ctxa[ii][jv] = MFMA(a2f[ii], vb[jv], ctxa[ii][jv]);
    }
  }
  asm volatile("" ::: "memory");  // fence u16/f32 LDS type-pun reordering
  // epilogue: transpose wave quadrant to [dd][m] via LDS (stride 68 f32), coalesced f32 writes
  float* lf = (float*)ktw;  // 32 x 68 f32 = 8704B <= 9216B
  float* dstb = ctx8 + (long)(nc * 96 + bh) * (MFEAT * DHEAD);
#pragma unroll
  for (int half = 0; half < 2; ++half) {
#pragma unroll
    for (int jh = 0; jh < 2; ++jh) {
      int jv = half * 2 + jh;
#pragma unroll
      for (int ii = 0; ii < 4; ++ii)
        *(f4v*)(lf + (jh * 16 + l15) * 68 + ii * 16 + lk * 4) =
            (f4v){ctxa[ii][jv][0], ctxa[ii][jv][1], ctxa[ii][jv][2], ctxa[ii][jv][3]};
    }
#pragma unroll
    for (int u = 0; u < 8; ++u) {
      int dd_l = u * 4 + lk;
      f4v v = *(const f4v*)(lf + dd_l * 68 + l15 * 4);
      *(f4v*)(dstb + (long)(half * 32 + dd_l) * MFEAT + wc + l15 * 4) = v;
    }
    asm volatile("" ::: "memory");
  }
#pragma unroll
  for (int j = 0; j < 4; ++j) {
    float s = cs[j];
    s += __shfl_xor(s, 16);
    s += __shfl_xor(s, 32);
    if (lk == 0) kpart[((long)bh * 8 + nc) * MFEAT + wc + j * 16 + l15] = s;
  }
}

// ---------------- K3b: Baug[bh][80][256] = [ctx^T ; k_sum ; 0] + f32 row-sums bsum[bh][80] ----------------
__global__ __launch_bounds__(256) void k3b(const float* __restrict__ ctx8, const float* __restrict__ kpart,
                                           u16* __restrict__ baug, float* __restrict__ bsum) {
  int bh = blockIdx.x, y = blockIdx.y;
  int tid = threadIdx.x;
  u16* o = baug + (long)bh * 80 * MFEAT;
  if (y < 4) {
    int dd = y * 16 + (tid >> 4);
    int m0 = (tid & 15) * 16;
    f4v s[4];
#pragma unroll
    for (int e = 0; e < 4; ++e) s[e] = (f4v){0.f, 0.f, 0.f, 0.f};
    for (int c = 0; c < 8; ++c) {
      const float* r = ctx8 + (long)(c * 96 + bh) * (MFEAT * DHEAD) + dd * MFEAT + m0;
#pragma unroll
      for (int e = 0; e < 4; ++e) s[e] += *(const f4v*)(r + e * 4);
    }
    float t = 0.f;
#pragma unroll
    for (int e = 0; e < 4; ++e) {
      us4 w;
#pragma unroll
      for (int q = 0; q < 4; ++q) { t += s[e][q]; w[q] = f2bf(s[e][q]); }
      *(us4*)(o + dd * MFEAT + m0 + e * 4) = w;
    }
    t += __shfl_xor(t, 1); t += __shfl_xor(t, 2); t += __shfl_xor(t, 4); t += __shfl_xor(t, 8);
    if ((tid & 15) == 0) bsum[bh * 80 + dd] = t;
  } else {
    __shared__ float red[4];
    int m = tid;
    float ks = 0.f;
    for (int c = 0; c < 8; ++c) ks += kpart[((long)bh * 8 + c) * MFEAT + m];
    o[64 * MFEAT + m] = f2bf(ks);
    float t = ks;
    t += __shfl_xor(t, 1); t += __shfl_xor(t, 2); t += __shfl_xor(t, 4);
    t += __shfl_xor(t, 8); t += __shfl_xor(t, 16); t += __shfl_xor(t, 32);
    if ((m & 63) == 0) red[m >> 6] = t;
    __syncthreads();
    if (m == 0) bsum[bh * 80 + 64] = red[0] + red[1] + red[2] + red[3];
    for (int dd = 65; dd < 80; ++dd) o[dd * MFEAT + m] = 0;
    if (m < 15) bsum[bh * 80 + 65 + m] = 0.f;
  }
}

// ---------------- K2Q5: fused phi(q) + (q' @ Baug^T), online max, analytic eps ----------------
__global__ __launch_bounds__(256) void k2q5(const u16* __restrict__ qb, const u16* __restrict__ projb,
                                            const u16* __restrict__ baug, const float* __restrict__ bsum,
                                            u16* __restrict__ attn) {
  __shared__ u16 smem[4 * 64 * 72];
  int bh = blockIdx.y;
  int b = bh / H_, h = bh % H_;
  int tid = threadIdx.x, lane = tid & 63, wid = tid >> 6;
  int l15 = lane & 15, lk = lane >> 4;
  int tb = blockIdx.x * 256 + wid * 64;  // wave's 64 tokens
  const u16* Aq = qb + ((long)bh * NTOK + tb) * DHEAD;
  const u16* Bb = baug + (long)bh * 80 * MFEAT;
  u16* qTw = smem + wid * 4608;  // loop: [64 tok][40]; epilogue: [64][72]

  // resident q fragments + diag (token = 16i+l15)
  s16x8 a2[4][2];
  float ssv[4] = {0.f, 0.f, 0.f, 0.f};
#pragma unroll
  for (int i = 0; i < 4; ++i)
#pragma unroll
    for (int ks = 0; ks < 2; ++ks) {
      a2[i][ks] = *(const s16x8*)(Aq + (long)(i * 16 + l15) * DHEAD + ks * 32 + lk * 8);
#pragma unroll
      for (int e = 0; e < 8; ++e) { float f = bf2f((u16)a2[i][ks][e]); ssv[i] += f * f; }
    }
  float dgv[4];
#pragma unroll
  for (int i = 0; i < 4; ++i) {
    float s = ssv[i];
    s += __shfl_xor(s, 16);
    s += __shfl_xor(s, 32);
    dgv[i] = s * DIAGSCALE;
  }
  float rm[4] = {-3.4e38f, -3.4e38f, -3.4e38f, -3.4e38f};
  f32x4 oacc[5][4];  // [baug-frag jo][token-frag i]; row=16jo+4lk+r, col(token)=16i+l15
#pragma unroll
  for (int jo = 0; jo < 5; ++jo)
#pragma unroll
    for (int i = 0; i < 4; ++i) oacc[jo][i] = (f32x4){0.f, 0.f, 0.f, 0.f};

  for (int c = 0; c < 8; ++c) {  // 32-feature chunks
    s16x8 pb[2][2];
#pragma unroll
    for (int j = 0; j < 2; ++j)
#pragma unroll
      for (int ks = 0; ks < 2; ++ks)
        pb[j][ks] = *(const s16x8*)(projb + (long)(c * 32 + j * 16 + l15) * DHEAD + ks * 32 + lk * 8);
    f32x4 dacc[2][4];
#pragma unroll
    for (int j = 0; j < 2; ++j)
#pragma unroll
      for (int i = 0; i < 4; ++i) dacc[j][i] = (f32x4){0.f, 0.f, 0.f, 0.f};
#pragma unroll
    for (int ks = 0; ks < 2; ++ks)
#pragma unroll
      for (int j = 0; j < 2; ++j)
#pragma unroll
        for (int i = 0; i < 4; ++i) dacc[j][i] = MFMA(pb[j][ks], a2[i][ks], dacc[j][i]);
    float fsc[4];
#pragma unroll
    for (int i = 0; i < 4; ++i) {
      float cm = dacc[0][i][0];
      cm = fmaxf(cm, dacc[0][i][1]); cm = fmaxf(cm, dacc[0][i][2]); cm = fmaxf(cm, dacc[0][i][3]);
      cm = fmaxf(cm, dacc[1][i][0]); cm = fmaxf(cm, dacc[1][i][1]);
      cm = fmaxf(cm, dacc[1][i][2]); cm = fmaxf(cm, dacc[1][i][3]);
      cm = fmaxf(cm, __shfl_xor(cm, 16));
      cm = fmaxf(cm, __shfl_xor(cm, 32));
      float rn = fmaxf(rm[i], cm);
      fsc[i] = __expf((rm[i] - rn) * NORMALIZER);
      rm[i] = rn;
    }
#pragma unroll
    for (int jo = 0; jo < 5; ++jo)
#pragma unroll
      for (int i = 0; i < 4; ++i) oacc[jo][i] *= fsc[i];
    // phi (NO eps -- handled analytically) -> wave-local LDS [64 tok][40]
#pragma unroll
    for (int i = 0; i < 4; ++i) {
      float dm = dgv[i] + rm[i] * NORMALIZER;
#pragma unroll
      for (int j = 0; j < 2; ++j) {
        us4 w;
#pragma unroll
        for (int r = 0; r < 4; ++r)
          w[r] = f2bf(RATIO_ * __expf(dacc[j][i][r] * NORMALIZER - dm));
        *(us4*)(qTw + (i * 16 + l15) * 40 + j * 16 + lk * 4) = w;
      }
    }
    s16x8 bB[5], qf[4];
#pragma unroll
    for (int jo = 0; jo < 5; ++jo)
      bB[jo] = *(const s16x8*)(Bb + (long)(jo * 16 + l15) * MFEAT + c * 32 + lk * 8);
#pragma unroll
    for (int i = 0; i < 4; ++i)
      qf[i] = *(const s16x8*)(qTw + (i * 16 + l15) * 40 + lk * 8);
#pragma unroll
    for (int jo = 0; jo < 5; ++jo)
#pragma unroll
      for (int i = 0; i < 4; ++i) oacc[jo][i] = MFMA(bB[jo], qf[i], oacc[jo][i]);
  }
  // analytic eps term: out += ratio*eps*rowsum(Baug[br]) (exact, unaffected by rescale)
#pragma unroll
  for (int jo = 0; jo < 5; ++jo) {
    f4v bs = *(const f4v*)(bsum + (long)bh * 80 + jo * 16 + lk * 4);
#pragma unroll
    for (int i = 0; i < 4; ++i)
#pragma unroll
      for (int r = 0; r < 4; ++r) oacc[jo][i][r] += (RATIO_ * EPS_) * bs[r];
  }
  // epilogue: divide by denominator, stage, write
  u16* stw = qTw;  // stride 72 now
#pragma unroll
  for (int i = 0; i < 4; ++i) {
    float dn = __shfl(oacc[4][i][0], l15);  // token 16i+l15's denom from lane (l15, lk=0)
    float inv = 1.0f / dn;
#pragma unroll
    for (int jo = 0; jo < 4; ++jo) {
      us4 w;
#pragma unroll
      for (int r = 0; r < 4; ++r) w[r] = f2bf(oacc[jo][i][r] * inv);
      *(us4*)(stw + (i * 16 + l15) * 72 + jo * 16 + lk * 4) = w;
    }
  }
  u16* dst = attn + ((long)b * NTOK + tb) * CDIM + h * DHEAD;
  st_write64(stw, dst, CDIM, lane);
}

// ---------------- K6: out = attn @ w_proj^T + b_proj (128x256 tile, 4x8 frags, fp32 out) ----------------
__global__ __launch_bounds__(256) void k6_proj(const u16* __restrict__ A, const u16* __restrict__ Bm,
                                               const float* __restrict__ bproj, float* __restrict__ out) {
  __shared__ u16 smem[24576];  // lA[0,8192) lB[8192,24576)
  u16* lA = smem;
  u16* lB = smem + 8192;
  int tid = threadIdx.x, lane = tid & 63, wid = tid >> 6;
  // XCD-concentration remap (bijective on [0,768))
  int p = blockIdx.x + blockIdx.y * 3;
  int r8 = p & 7, q = p >> 3;        // q in [0,96)
  int bx = q % 3;
  int by = (q / 3) * 8 + r8;
  int m0 = by << 7, n0 = bx << 8;
  int wr = (wid >> 1) << 6;          // {0,64}
  int wc = (wid & 1) << 7;           // {0,128}
  int l15 = lane & 15, lk = lane >> 4;
  int lr = lane >> 3;
  int lu = (lane & 7) ^ lr;
  const u16* Ab = A + (long)m0 * CDIM;
  const u16* Bb = Bm + (long)n0 * CDIM;
  const u16* gA = Ab + (long)(wid * 32 + lr) * CDIM + lu * 8;
  const u16* gB = Bb + (long)(wid * 64 + lr) * CDIM + lu * 8;
  u16* dA = lA + wid * 2048;
  u16* dB = lB + wid * 4096;
  f32x4 acc[4][8];
#pragma unroll
  for (int i = 0; i < 4; ++i)
#pragma unroll
    for (int j = 0; j < 8; ++j) acc[i][j] = (f32x4){0.f, 0.f, 0.f, 0.f};
  for (int k0 = 0; k0 < CDIM; k0 += 64) {
    __syncthreads();
#pragma unroll
    for (int g = 0; g < 4; ++g)
      glds16(gA + k0 + (long)g * 8 * CDIM, dA + g * 512);
#pragma unroll
    for (int g = 0; g < 8; ++g)
      glds16(gB + k0 + (long)g * 8 * CDIM, dB + g * 512);
    __syncthreads();
#pragma unroll
    for (int ks = 0; ks < 2; ++ks) {
      s16x8 af[4], bv[8];
      int co = ((ks * 4 + lk) ^ (l15 & 7)) * 8;
#pragma unroll
      for (int i = 0; i < 4; ++i)
        af[i] = *(const s16x8*)(lA + (wr + i * 16 + l15) * 64 + co);
#pragma unroll
      for (int j = 0; j < 8; ++j)
        bv[j] = *(const s16x8*)(lB + (wc + j * 16 + l15) * 64 + co);
#pragma unroll
      for (int i = 0; i < 4; ++i)
#pragma unroll
        for (int j = 0; j < 8; ++j) acc[i][j] = MFMA(af[i], bv[j], acc[i][j]);
    }
  }
  float bpv[8];
#pragma unroll
  for (int j = 0; j < 8; ++j) bpv[j] = bproj[n0 + wc + j * 16 + l15];
#pragma unroll
  for (int i = 0; i < 4; ++i)
#pragma unroll
    for (int j = 0; j < 8; ++j)
#pragma unroll
      for (int r = 0; r < 4; ++r) {
        long row = m0 + wr + i * 16 + lk * 4 + r;
        int col = n0 + wc + j * 16 + l15;
        out[row * CDIM + col] = acc[i][j][r] + bpv[j];
      }
}

extern "C" void kernel_launch(void* const* d_in, const int* in_sizes, int n_in,
                              void* d_out, int out_size, void* d_ws, size_t ws_size,
                              hipStream_t stream) {
  const float* x = (const float*)d_in[0];
  const float* w_qkv = (const float*)d_in[1];
  const float* w_proj = (const float*)d_in[2];
  const float* b_proj = (const float*)d_in[3];
  const float* proj = (const float*)d_in[4];
  float* out = (float*)d_out;

  char* p = (char*)d_ws;
  auto take = [&](size_t bytes) {
    char* r = p;
    p += (bytes + 255) & ~(size_t)255;
    return r;
  };
  u16* xb = (u16*)take(32768UL * 768 * 2);      // 50.33 MB; dead after k0 -> ctx8
  u16* wqkvb = (u16*)take(2304UL * 768 * 2);
  u16* wprojb = (u16*)take(768UL * 768 * 2);
  u16* projb = (u16*)take(256UL * 64 * 2);
  u16* qb = (u16*)take(96UL * 4096 * 64 * 2);   // 50.33 MB
  u16* kb = (u16*)take(96UL * 4096 * 64 * 2);   // 50.33 MB; dead after k3f -> attn
  u16* vT = (u16*)take(96UL * 64 * 4096 * 2);   // 50.33 MB
  float* kpart = (float*)take(96UL * 8 * 256 * 4);
  u32* mk = (u32*)take(256);
  u16* baug = (u16*)take(96UL * 80 * 256 * 2);
  float* bsum = (float*)take(96UL * 80 * 4);
  // stream-ordered aliases
  float* ctx8 = (float*)xb;  // [8][96][64][256] f32 == 50.33 MB exactly
  u16* attn = kb;            // 50.33 MB

  cvt_all<<<26896, 256, 0, stream>>>(x, w_qkv, w_proj, proj, xb, wqkvb, wprojb, projb, mk);
  k0_qkv<<<dim3(9, 256), 256, 0, stream>>>(xb, wqkvb, qb, kb, vT);
  k2_k1<<<dim3(64, 96), 256, 0, stream>>>(kb, projb, mk);
  k3f<<<dim3(8, 96), 256, 0, stream>>>(kb, vT, projb, mk, ctx8, kpart);
  k3b<<<dim3(96, 5), 256, 0, stream>>>(ctx8, kpart, baug, bsum);
  k2q5<<<dim3(16, 96), 256, 0, stream>>>(qb, projb, baug, bsum, attn);
  k6_proj<<<dim3(3, 256), 256, 0, stream>>>(attn, wprojb, b_proj, out);
}

// Round 12
// 497.068 us; speedup vs baseline: 1.2227x; 1.2227x over previous
//
#include <hip/hip_runtime.h>
#include <hip/hip_bf16.h>

typedef __attribute__((ext_vector_type(4))) float f32x4;
typedef __attribute__((ext_vector_type(8))) short s16x8;
typedef __attribute__((ext_vector_type(4))) float f4v;
typedef __attribute__((ext_vector_type(4))) unsigned short us4;
typedef unsigned short u16;
typedef unsigned int u32;

#define H_ 12
#define NTOK 4096
#define DHEAD 64
#define MFEAT 256
#define CDIM 768

#define NORMALIZER 0.35355339059327373f  /* 64^-0.25 */
#define DIAGSCALE 0.0625f                /* 0.5 * NORMALIZER^2 */
#define RATIO_ 0.0625f                   /* 256^-0.5 */
#define EPS_ 1e-4f

#define MFMA(a, b, c) __builtin_amdgcn_mfma_f32_16x16x32_bf16((a), (b), (c), 0, 0, 0)

__device__ __forceinline__ float bf2f(u16 u) {
  union { float f; u32 v; } x; x.v = ((u32)u) << 16; return x.f;
}
__device__ __forceinline__ u16 f2bf(float f) {
  union { float f; u32 v; } x; x.f = f;
  u32 v = x.v + 0x7FFFu + ((x.v >> 16) & 1u);
  return (u16)(v >> 16);
}
__device__ __forceinline__ u32 fenc(float f) {
  u32 u = __float_as_uint(f);
  return (u & 0x80000000u) ? ~u : (u | 0x80000000u);
}
__device__ __forceinline__ float fdec(u32 k) {
  u32 u = (k & 0x80000000u) ? (k & 0x7fffffffu) : ~k;
  return __uint_as_float(u);
}
__device__ __forceinline__ void glds16(const u16* g, u16* l) {
  __builtin_amdgcn_global_load_lds((const __attribute__((address_space(1))) void*)g,
                                   (__attribute__((address_space(3))) void*)l, 16, 0, 0);
}

// write a wave's staged 64x64 bf16 tile (rows padded to 72) to dst
__device__ __forceinline__ void st_write64(const u16* stw, u16* dst, long ld, int lane) {
  int r0 = lane >> 3, cc = lane & 7;
#pragma unroll
  for (int c = 0; c < 8; ++c) {
    int row = c * 8 + r0;
    s16x8 v = *(const s16x8*)(stw + row * 72 + cc * 8);
    *(s16x8*)(dst + (long)row * ld + cc * 8) = v;
  }
}

// ---------------- fused init + fp32->bf16 converts (block-aligned segments) ----------------
__global__ void cvt_all(const float* __restrict__ x, const float* __restrict__ wq,
                        const float* __restrict__ wp, const float* __restrict__ pj,
                        u16* __restrict__ xb, u16* __restrict__ wqb,
                        u16* __restrict__ wpb, u16* __restrict__ pjb, u32* __restrict__ mk) {
  int b = blockIdx.x;
  if (b == 0 && threadIdx.x < 8) mk[threadIdx.x] = 0u;
  const float* s;
  u16* d;
  int base;
  if (b < 24576)      { s = x;  d = xb;  base = b; }
  else if (b < 26304) { s = wq; d = wqb; base = b - 24576; }
  else if (b < 26880) { s = wp; d = wpb; base = b - 26304; }
  else                { s = pj; d = pjb; base = b - 26880; }
  long i = (long)base * 256 + threadIdx.x;
  f4v v = *(const f4v*)(s + i * 4);
  us4 o;
#pragma unroll
  for (int j = 0; j < 4; ++j) o[j] = f2bf(v[j]);
  *(us4*)(d + i * 4) = o;
}

// ---------------- K0: QKV GEMM, BK=64 glds16, XCD-concentrated panel groups (round-9 proven) ----------------
__global__ __launch_bounds__(256) void k0_qkv(const u16* __restrict__ A, const u16* __restrict__ Bm,
                                              u16* __restrict__ qb, u16* __restrict__ kb,
                                              u16* __restrict__ vT) {
  __shared__ u16 smem[4 * 64 * 72];   // loop: lA[0,8192) lB[8192,16384) u16; epilogue: 4x 64x72
  u16* lA = smem;
  u16* lB = smem + 8192;
  int tid = threadIdx.x, lane = tid & 63, wid = tid >> 6;
  // XCD-concentration remap (bijective on [0,4608))
  int p = blockIdx.x + blockIdx.y * 18;
  int r8 = p & 7, q = p >> 3;        // q in [0,576)
  int bx = q % 18;                   // N-panel member
  int by = (q / 18) * 8 + r8;        // M-panel group (same XCD for all 18 members)
  int m0 = by << 7, n0 = bx << 7;
  int wr = (wid >> 1) << 6, wc = (wid & 1) << 6;
  int l15 = lane & 15, lk = lane >> 4;
  int lr = lane >> 3;            // row within 8-row group
  int lu = (lane & 7) ^ lr;      // pre-swizzled source 16B-unit
  const u16* Ab = A + (long)m0 * CDIM;
  const u16* Bb = Bm + (long)n0 * CDIM;
  const u16* gA = Ab + (long)(wid * 32 + lr) * CDIM + lu * 8;
  const u16* gB = Bb + (long)(wid * 32 + lr) * CDIM + lu * 8;
  u16* dA = lA + wid * 2048;
  u16* dB = lB + wid * 2048;
  f32x4 acc[4][4];
#pragma unroll
  for (int i = 0; i < 4; ++i)
#pragma unroll
    for (int j = 0; j < 4; ++j) acc[i][j] = (f32x4){0.f, 0.f, 0.f, 0.f};
  for (int k0 = 0; k0 < CDIM; k0 += 64) {
    __syncthreads();
#pragma unroll
    for (int g = 0; g < 4; ++g) {
      glds16(gA + k0 + (long)g * 8 * CDIM, dA + g * 512);
      glds16(gB + k0 + (long)g * 8 * CDIM, dB + g * 512);
    }
    __syncthreads();
#pragma unroll
    for (int ks = 0; ks < 2; ++ks) {
      s16x8 af[4], bv[4];
#pragma unroll
      for (int i = 0; i < 4; ++i) {
        int co = ((ks * 4 + lk) ^ (l15 & 7)) * 8;   // swizzled read unit
        af[i] = *(const s16x8*)(lA + (wr + i * 16 + l15) * 64 + co);
        bv[i] = *(const s16x8*)(lB + (wc + i * 16 + l15) * 64 + co);
      }
#pragma unroll
      for (int i = 0; i < 4; ++i)
#pragma unroll
        for (int j = 0; j < 4; ++j) acc[i][j] = MFMA(af[i], bv[j], acc[i][j]);
    }
  }
  __syncthreads();  // before reusing smem as epilogue stage
  int colbase = n0 + wc;
  int qi = colbase / CDIM;
  int h = (colbase % CDIM) >> 6;
  int rowbase = m0 + wr;
  int b = rowbase >> 12;
  int nloc = rowbase & (NTOK - 1);
  u16* stw = smem + wid * 4608;
  if (qi < 2) {
#pragma unroll
    for (int i = 0; i < 4; ++i)
#pragma unroll
      for (int j = 0; j < 4; ++j)
#pragma unroll
        for (int r = 0; r < 4; ++r)
          stw[(i * 16 + lk * 4 + r) * 72 + j * 16 + l15] = f2bf(acc[i][j][r]);
    u16* dst = (qi == 0 ? qb : kb) + ((long)(b * H_ + h) * NTOK + nloc) * DHEAD;
    st_write64(stw, dst, DHEAD, lane);
  } else {
    // transposed stage: st[dd][n] (pack 4 r's into one b64)
#pragma unroll
    for (int i = 0; i < 4; ++i)
#pragma unroll
      for (int j = 0; j < 4; ++j) {
        us4 w;
#pragma unroll
        for (int r = 0; r < 4; ++r) w[r] = f2bf(acc[i][j][r]);
        *(us4*)(stw + (j * 16 + l15) * 72 + i * 16 + lk * 4) = w;
      }
    u16* dst = vT + (long)(b * H_ + h) * DHEAD * NTOK + nloc;
    st_write64(stw, dst, NTOK, lane);
  }
}

// ---------------- K2k pass1: global max of k_dash per batch ----------------
__global__ __launch_bounds__(256) void k2_k1(const u16* __restrict__ kb, const u16* __restrict__ projb,
                                             u32* __restrict__ mk) {
  __shared__ float wmax[4];
  int bh = blockIdx.y;
  int n0 = blockIdx.x << 6;
  const u16* Aq = kb + ((long)bh * NTOK + n0) * DHEAD;
  int tid = threadIdx.x, lane = tid & 63, wid = tid >> 6;
  int wc = wid << 6;
  int l15 = lane & 15, lk = lane >> 4;
  f32x4 acc[4][4];
#pragma unroll
  for (int i = 0; i < 4; ++i)
#pragma unroll
    for (int j = 0; j < 4; ++j) acc[i][j] = (f32x4){0.f, 0.f, 0.f, 0.f};
  __builtin_amdgcn_s_setprio(1);
#pragma unroll
  for (int ks = 0; ks < 2; ++ks) {
    s16x8 a[4], bv[4];
#pragma unroll
    for (int i = 0; i < 4; ++i)
      a[i] = *(const s16x8*)(Aq + (long)(i * 16 + l15) * DHEAD + ks * 32 + lk * 8);
#pragma unroll
    for (int j = 0; j < 4; ++j)
      bv[j] = *(const s16x8*)(projb + (long)(wc + j * 16 + l15) * DHEAD + ks * 32 + lk * 8);
#pragma unroll
    for (int i = 0; i < 4; ++i)
#pragma unroll
      for (int j = 0; j < 4; ++j) acc[i][j] = MFMA(a[i], bv[j], acc[i][j]);
  }
  __builtin_amdgcn_s_setprio(0);
  float m = -3.4e38f;
#pragma unroll
  for (int i = 0; i < 4; ++i)
#pragma unroll
    for (int j = 0; j < 4; ++j)
#pragma unroll
      for (int r = 0; r < 4; ++r) m = fmaxf(m, acc[i][j][r]);
  m = fmaxf(m, __shfl_xor(m, 1));
  m = fmaxf(m, __shfl_xor(m, 2));
  m = fmaxf(m, __shfl_xor(m, 4));
  m = fmaxf(m, __shfl_xor(m, 8));
  m = fmaxf(m, __shfl_xor(m, 16));
  m = fmaxf(m, __shfl_xor(m, 32));
  if (lane == 0) wmax[wid] = m;
  __syncthreads();
  if (tid == 0) {
    float mm = fmaxf(fmaxf(wmax[0], wmax[1]), fmaxf(wmax[2], wmax[3])) * NORMALIZER;
    atomicMax(mk + (blockIdx.y / H_), fenc(mm));
  }
}

// ---------------- K3f: fused phi(k) + context = k'^T @ v (512-token chunk, barrier-free) ----------------
// ctx8 layout: [nc][bh][dd][m]  (dd-major, coalesced for k3b)
__global__ __launch_bounds__(256) void k3f(const u16* __restrict__ kb, const u16* __restrict__ vT,
                                           const u16* __restrict__ projb, const u32* __restrict__ mk,
                                           float* __restrict__ ctx8, float* __restrict__ kpart) {
  __shared__ u16 smem[4 * 64 * 72];
  int bh = blockIdx.y, nc = blockIdx.x;  // nc in [0,8)
  int tid = threadIdx.x, lane = tid & 63, wid = tid >> 6;
  int l15 = lane & 15, lk = lane >> 4;
  int wc = wid << 6;
  float mg = fdec(mk[bh / H_]);
  const u16* Kb = kb + ((long)bh * NTOK + nc * 512) * DHEAD;
  const u16* Vb = vT + (long)bh * DHEAD * NTOK + nc * 512;
  u16* ktw = smem + wid * 4608;  // per-wave 9216B tile (wave-local!)
  f32x4 ctxa[4][4];
#pragma unroll
  for (int i = 0; i < 4; ++i)
#pragma unroll
    for (int j = 0; j < 4; ++j) ctxa[i][j] = (f32x4){0.f, 0.f, 0.f, 0.f};
  float cs[4] = {0.f, 0.f, 0.f, 0.f};
  for (int sb = 0; sb < 8; ++sb) {
    const u16* Ksb = Kb + sb * 64 * DHEAD;
    s16x8 a[4][2];
    float ss[4] = {0.f, 0.f, 0.f, 0.f};
#pragma unroll
    for (int i = 0; i < 4; ++i)
#pragma unroll
      for (int ks = 0; ks < 2; ++ks) {
        a[i][ks] = *(const s16x8*)(Ksb + (long)(i * 16 + l15) * DHEAD + ks * 32 + lk * 8);
#pragma unroll
        for (int e = 0; e < 8; ++e) { float f = bf2f((u16)a[i][ks][e]); ss[i] += f * f; }
      }
    float dgv[4];
#pragma unroll
    for (int i = 0; i < 4; ++i) {
      float s = ss[i];
      s += __shfl_xor(s, 16);
      s += __shfl_xor(s, 32);
      dgv[i] = s * DIAGSCALE;  // diag of token 16i+l15 (uniform over lk)
    }
    f32x4 dacc[4][4];
#pragma unroll
    for (int i = 0; i < 4; ++i)
#pragma unroll
      for (int j = 0; j < 4; ++j) dacc[i][j] = (f32x4){0.f, 0.f, 0.f, 0.f};
    __builtin_amdgcn_s_setprio(1);
#pragma unroll
    for (int ks = 0; ks < 2; ++ks)
#pragma unroll
      for (int j = 0; j < 4; ++j) {
        s16x8 pb = *(const s16x8*)(projb + (long)(wc + j * 16 + l15) * DHEAD + ks * 32 + lk * 8);
#pragma unroll
        for (int i = 0; i < 4; ++i) dacc[i][j] = MFMA(a[i][ks], pb, dacc[i][j]);
      }
    __builtin_amdgcn_s_setprio(0);
    // diag at token 16i+4lk+r via shuffle
    float dgr[4][4];
#pragma unroll
    for (int i = 0; i < 4; ++i)
#pragma unroll
      for (int r = 0; r < 4; ++r) dgr[i][r] = __shfl(dgv[i], 4 * lk + r);
    // phi -> kT (wave-local), packed b64 writes
#pragma unroll
    for (int i = 0; i < 4; ++i)
#pragma unroll
      for (int j = 0; j < 4; ++j) {
        us4 w;
#pragma unroll
        for (int r = 0; r < 4; ++r) {
          float v = RATIO_ * (__expf(dacc[i][j][r] * NORMALIZER - dgr[i][r] - mg) + EPS_);
          cs[j] += v;
          w[r] = f2bf(v);
        }
        *(us4*)(ktw + (j * 16 + l15) * 72 + i * 16 + lk * 4) = w;
      }
    // context MFMA: A = k'(features) rows from ktw, B = vT rows
    __builtin_amdgcn_s_setprio(1);
#pragma unroll
    for (int ks = 0; ks < 2; ++ks) {
      s16x8 a2f[4], vb[4];
#pragma unroll
      for (int ii = 0; ii < 4; ++ii)
        a2f[ii] = *(const s16x8*)(ktw + (ii * 16 + l15) * 72 + ks * 32 + lk * 8);
#pragma unroll
      for (int jv = 0; jv < 4; ++jv)
        vb[jv] = *(const s16x8*)(Vb + (long)(jv * 16 + l15) * NTOK + sb * 64 + ks * 32 + lk * 8);
#pragma unroll
      for (int ii = 0; ii < 4; ++ii)
#pragma unroll
        for (int jv = 0; jv < 4; ++jv) ctxa[ii][jv] = MFMA(a2f[ii], vb[jv], ctxa[ii][jv]);
    }
    __builtin_amdgcn_s_setprio(0);
  }
  asm volatile("" ::: "memory");  // fence u16/f32 LDS type-pun reordering
  // epilogue: transpose wave quadrant to [dd][m] via LDS (stride 68 f32), coalesced f32 writes
  float* lf = (float*)ktw;  // 32 x 68 f32 = 8704B <= 9216B
  float* dstb = ctx8 + (long)(nc * 96 + bh) * (MFEAT * DHEAD);
#pragma unroll
  for (int half = 0; half < 2; ++half) {
#pragma unroll
    for (int jh = 0; jh < 2; ++jh) {
      int jv = half * 2 + jh;
#pragma unroll
      for (int ii = 0; ii < 4; ++ii)
        *(f4v*)(lf + (jh * 16 + l15) * 68 + ii * 16 + lk * 4) =
            (f4v){ctxa[ii][jv][0], ctxa[ii][jv][1], ctxa[ii][jv][2], ctxa[ii][jv][3]};
    }
#pragma unroll
    for (int u = 0; u < 8; ++u) {
      int dd_l = u * 4 + lk;
      f4v v = *(const f4v*)(lf + dd_l * 68 + l15 * 4);
      *(f4v*)(dstb + (long)(half * 32 + dd_l) * MFEAT + wc + l15 * 4) = v;
    }
    asm volatile("" ::: "memory");
  }
#pragma unroll
  for (int j = 0; j < 4; ++j) {
    float s = cs[j];
    s += __shfl_xor(s, 16);
    s += __shfl_xor(s, 32);
    if (lk == 0) kpart[((long)bh * 8 + nc) * MFEAT + wc + j * 16 + l15] = s;
  }
}

// ---------------- K3b: Baug[bh][80][256] = [ctx^T ; k_sum ; 0] + f32 row-sums bsum[bh][80] ----------------
__global__ __launch_bounds__(256) void k3b(const float* __restrict__ ctx8, const float* __restrict__ kpart,
                                           u16* __restrict__ baug, float* __restrict__ bsum) {
  int bh = blockIdx.x, y = blockIdx.y;
  int tid = threadIdx.x;
  u16* o = baug + (long)bh * 80 * MFEAT;
  if (y < 4) {
    int dd = y * 16 + (tid >> 4);
    int m0 = (tid & 15) * 16;
    f4v s[4];
#pragma unroll
    for (int e = 0; e < 4; ++e) s[e] = (f4v){0.f, 0.f, 0.f, 0.f};
    for (int c = 0; c < 8; ++c) {
      const float* r = ctx8 + (long)(c * 96 + bh) * (MFEAT * DHEAD) + dd * MFEAT + m0;
#pragma unroll
      for (int e = 0; e < 4; ++e) s[e] += *(const f4v*)(r + e * 4);
    }
    float t = 0.f;
#pragma unroll
    for (int e = 0; e < 4; ++e) {
      us4 w;
#pragma unroll
      for (int q = 0; q < 4; ++q) { t += s[e][q]; w[q] = f2bf(s[e][q]); }
      *(us4*)(o + dd * MFEAT + m0 + e * 4) = w;
    }
    t += __shfl_xor(t, 1); t += __shfl_xor(t, 2); t += __shfl_xor(t, 4); t += __shfl_xor(t, 8);
    if ((tid & 15) == 0) bsum[bh * 80 + dd] = t;
  } else {
    __shared__ float red[4];
    int m = tid;
    float ks = 0.f;
    for (int c = 0; c < 8; ++c) ks += kpart[((long)bh * 8 + c) * MFEAT + m];
    o[64 * MFEAT + m] = f2bf(ks);
    float t = ks;
    t += __shfl_xor(t, 1); t += __shfl_xor(t, 2); t += __shfl_xor(t, 4);
    t += __shfl_xor(t, 8); t += __shfl_xor(t, 16); t += __shfl_xor(t, 32);
    if ((m & 63) == 0) red[m >> 6] = t;
    __syncthreads();
    if (m == 0) bsum[bh * 80 + 64] = red[0] + red[1] + red[2] + red[3];
    for (int dd = 65; dd < 80; ++dd) o[dd * MFEAT + m] = 0;
    if (m < 15) bsum[bh * 80 + 65 + m] = 0.f;
  }
}

// ---------------- K2Q5: fused phi(q) + (q' @ Baug^T), online max, analytic eps ----------------
__global__ __launch_bounds__(256) void k2q5(const u16* __restrict__ qb, const u16* __restrict__ projb,
                                            const u16* __restrict__ baug, const float* __restrict__ bsum,
                                            u16* __restrict__ attn) {
  __shared__ u16 smem[4 * 64 * 72];
  int bh = blockIdx.y;
  int b = bh / H_, h = bh % H_;
  int tid = threadIdx.x, lane = tid & 63, wid = tid >> 6;
  int l15 = lane & 15, lk = lane >> 4;
  int tb = blockIdx.x * 256 + wid * 64;  // wave's 64 tokens
  const u16* Aq = qb + ((long)bh * NTOK + tb) * DHEAD;
  const u16* Bb = baug + (long)bh * 80 * MFEAT;
  u16* qTw = smem + wid * 4608;  // loop: [64 tok][40]; epilogue: [64][72]

  // resident q fragments + diag (token = 16i+l15)
  s16x8 a2[4][2];
  float ssv[4] = {0.f, 0.f, 0.f, 0.f};
#pragma unroll
  for (int i = 0; i < 4; ++i)
#pragma unroll
    for (int ks = 0; ks < 2; ++ks) {
      a2[i][ks] = *(const s16x8*)(Aq + (long)(i * 16 + l15) * DHEAD + ks * 32 + lk * 8);
#pragma unroll
      for (int e = 0; e < 8; ++e) { float f = bf2f((u16)a2[i][ks][e]); ssv[i] += f * f; }
    }
  float dgv[4];
#pragma unroll
  for (int i = 0; i < 4; ++i) {
    float s = ssv[i];
    s += __shfl_xor(s, 16);
    s += __shfl_xor(s, 32);
    dgv[i] = s * DIAGSCALE;
  }
  float rm[4] = {-3.4e38f, -3.4e38f, -3.4e38f, -3.4e38f};
  f32x4 oacc[5][4];  // [baug-frag jo][token-frag i]; row=16jo+4lk+r, col(token)=16i+l15
#pragma unroll
  for (int jo = 0; jo < 5; ++jo)
#pragma unroll
    for (int i = 0; i < 4; ++i) oacc[jo][i] = (f32x4){0.f, 0.f, 0.f, 0.f};

  for (int c = 0; c < 8; ++c) {  // 32-feature chunks
    s16x8 pb[2][2];
#pragma unroll
    for (int j = 0; j < 2; ++j)
#pragma unroll
      for (int ks = 0; ks < 2; ++ks)
        pb[j][ks] = *(const s16x8*)(projb + (long)(c * 32 + j * 16 + l15) * DHEAD + ks * 32 + lk * 8);
    f32x4 dacc[2][4];
#pragma unroll
    for (int j = 0; j < 2; ++j)
#pragma unroll
      for (int i = 0; i < 4; ++i) dacc[j][i] = (f32x4){0.f, 0.f, 0.f, 0.f};
    __builtin_amdgcn_s_setprio(1);
#pragma unroll
    for (int ks = 0; ks < 2; ++ks)
#pragma unroll
      for (int j = 0; j < 2; ++j)
#pragma unroll
        for (int i = 0; i < 4; ++i) dacc[j][i] = MFMA(pb[j][ks], a2[i][ks], dacc[j][i]);
    __builtin_amdgcn_s_setprio(0);
    float fsc[4];
#pragma unroll
    for (int i = 0; i < 4; ++i) {
      float cm = dacc[0][i][0];
      cm = fmaxf(cm, dacc[0][i][1]); cm = fmaxf(cm, dacc[0][i][2]); cm = fmaxf(cm, dacc[0][i][3]);
      cm = fmaxf(cm, dacc[1][i][0]); cm = fmaxf(cm, dacc[1][i][1]);
      cm = fmaxf(cm, dacc[1][i][2]); cm = fmaxf(cm, dacc[1][i][3]);
      cm = fmaxf(cm, __shfl_xor(cm, 16));
      cm = fmaxf(cm, __shfl_xor(cm, 32));
      float rn = fmaxf(rm[i], cm);
      fsc[i] = __expf((rm[i] - rn) * NORMALIZER);
      rm[i] = rn;
    }
#pragma unroll
    for (int jo = 0; jo < 5; ++jo)
#pragma unroll
      for (int i = 0; i < 4; ++i) oacc[jo][i] *= fsc[i];
    // phi (NO eps -- handled analytically) -> wave-local LDS [64 tok][40]
#pragma unroll
    for (int i = 0; i < 4; ++i) {
      float dm = dgv[i] + rm[i] * NORMALIZER;
#pragma unroll
      for (int j = 0; j < 2; ++j) {
        us4 w;
#pragma unroll
        for (int r = 0; r < 4; ++r)
          w[r] = f2bf(RATIO_ * __expf(dacc[j][i][r] * NORMALIZER - dm));
        *(us4*)(qTw + (i * 16 + l15) * 40 + j * 16 + lk * 4) = w;
      }
    }
    s16x8 bB[5], qf[4];
#pragma unroll
    for (int jo = 0; jo < 5; ++jo)
      bB[jo] = *(const s16x8*)(Bb + (long)(jo * 16 + l15) * MFEAT + c * 32 + lk * 8);
#pragma unroll
    for (int i = 0; i < 4; ++i)
      qf[i] = *(const s16x8*)(qTw + (i * 16 + l15) * 40 + lk * 8);
    __builtin_amdgcn_s_setprio(1);
#pragma unroll
    for (int jo = 0; jo < 5; ++jo)
#pragma unroll
      for (int i = 0; i < 4; ++i) oacc[jo][i] = MFMA(bB[jo], qf[i], oacc[jo][i]);
    __builtin_amdgcn_s_setprio(0);
  }
  // analytic eps term: out += ratio*eps*rowsum(Baug[br]) (exact, unaffected by rescale)
#pragma unroll
  for (int jo = 0; jo < 5; ++jo) {
    f4v bs = *(const f4v*)(bsum + (long)bh * 80 + jo * 16 + lk * 4);
#pragma unroll
    for (int i = 0; i < 4; ++i)
#pragma unroll
      for (int r = 0; r < 4; ++r) oacc[jo][i][r] += (RATIO_ * EPS_) * bs[r];
  }
  // epilogue: divide by denominator, stage, write
  u16* stw = qTw;  // stride 72 now
#pragma unroll
  for (int i = 0; i < 4; ++i) {
    float dn = __shfl(oacc[4][i][0], l15);  // token 16i+l15's denom from lane (l15, lk=0)
    float inv = 1.0f / dn;
#pragma unroll
    for (int jo = 0; jo < 4; ++jo) {
      us4 w;
#pragma unroll
      for (int r = 0; r < 4; ++r) w[r] = f2bf(oacc[jo][i][r] * inv);
      *(us4*)(stw + (i * 16 + l15) * 72 + jo * 16 + lk * 4) = w;
    }
  }
  u16* dst = attn + ((long)b * NTOK + tb) * CDIM + h * DHEAD;
  st_write64(stw, dst, CDIM, lane);
}

// ---------------- K6: out = attn @ w_proj^T + b_proj (BK=64, XCD-concentrated, fp32 out) ----------------
__global__ __launch_bounds__(256) void k6_proj(const u16* __restrict__ A, const u16* __restrict__ Bm,
                                               const float* __restrict__ bproj, float* __restrict__ out) {
  __shared__ u16 smem[16384];  // lA[0,8192) lB[8192,16384)
  u16* lA = smem;
  u16* lB = smem + 8192;
  int tid = threadIdx.x, lane = tid & 63, wid = tid >> 6;
  // XCD-concentration remap (bijective on [0,1536))
  int p = blockIdx.x + blockIdx.y * 6;
  int r8 = p & 7, q = p >> 3;        // q in [0,192)
  int bx = q % 6;
  int by = (q / 6) * 8 + r8;
  int m0 = by << 7, n0 = bx << 7;
  int wr = (wid >> 1) << 6, wc = (wid & 1) << 6;
  int l15 = lane & 15, lk = lane >> 4;
  int lr = lane >> 3;
  int lu = (lane & 7) ^ lr;
  const u16* Ab = A + (long)m0 * CDIM;
  const u16* Bb = Bm + (long)n0 * CDIM;
  const u16* gA = Ab + (long)(wid * 32 + lr) * CDIM + lu * 8;
  const u16* gB = Bb + (long)(wid * 32 + lr) * CDIM + lu * 8;
  u16* dA = lA + wid * 2048;
  u16* dB = lB + wid * 2048;
  f32x4 acc[4][4];
#pragma unroll
  for (int i = 0; i < 4; ++i)
#pragma unroll
    for (int j = 0; j < 4; ++j) acc[i][j] = (f32x4){0.f, 0.f, 0.f, 0.f};
  for (int k0 = 0; k0 < CDIM; k0 += 64) {
    __syncthreads();
#pragma unroll
    for (int g = 0; g < 4; ++g) {
      glds16(gA + k0 + (long)g * 8 * CDIM, dA + g * 512);
      glds16(gB + k0 + (long)g * 8 * CDIM, dB + g * 512);
    }
    __syncthreads();
#pragma unroll
    for (int ks = 0; ks < 2; ++ks) {
      s16x8 af[4], bv[4];
#pragma unroll
      for (int i = 0; i < 4; ++i) {
        int co = ((ks * 4 + lk) ^ (l15 & 7)) * 8;
        af[i] = *(const s16x8*)(lA + (wr + i * 16 + l15) * 64 + co);
        bv[i] = *(const s16x8*)(lB + (wc + i * 16 + l15) * 64 + co);
      }
#pragma unroll
      for (int i = 0; i < 4; ++i)
#pragma unroll
        for (int j = 0; j < 4; ++j) acc[i][j] = MFMA(af[i], bv[j], acc[i][j]);
    }
  }
  float bpv[4];
#pragma unroll
  for (int j = 0; j < 4; ++j) bpv[j] = bproj[n0 + wc + j * 16 + l15];
#pragma unroll
  for (int i = 0; i < 4; ++i)
#pragma unroll
    for (int j = 0; j < 4; ++j)
#pragma unroll
      for (int r = 0; r < 4; ++r) {
        long row = m0 + wr + i * 16 + lk * 4 + r;
        int col = n0 + wc + j * 16 + l15;
        out[row * CDIM + col] = acc[i][j][r] + bpv[j];
      }
}

extern "C" void kernel_launch(void* const* d_in, const int* in_sizes, int n_in,
                              void* d_out, int out_size, void* d_ws, size_t ws_size,
                              hipStream_t stream) {
  const float* x = (const float*)d_in[0];
  const float* w_qkv = (const float*)d_in[1];
  const float* w_proj = (const float*)d_in[2];
  const float* b_proj = (const float*)d_in[3];
  const float* proj = (const float*)d_in[4];
  float* out = (float*)d_out;

  char* p = (char*)d_ws;
  auto take = [&](size_t bytes) {
    char* r = p;
    p += (bytes + 255) & ~(size_t)255;
    return r;
  };
  u16* xb = (u16*)take(32768UL * 768 * 2);      // 50.33 MB; dead after k0 -> ctx8
  u16* wqkvb = (u16*)take(2304UL * 768 * 2);
  u16* wprojb = (u16*)take(768UL * 768 * 2);
  u16* projb = (u16*)take(256UL * 64 * 2);
  u16* qb = (u16*)take(96UL * 4096 * 64 * 2);   // 50.33 MB
  u16* kb = (u16*)take(96UL * 4096 * 64 * 2);   // 50.33 MB; dead after k3f -> attn
  u16* vT = (u16*)take(96UL * 64 * 4096 * 2);   // 50.33 MB
  float* kpart = (float*)take(96UL * 8 * 256 * 4);
  u32* mk = (u32*)take(256);
  u16* baug = (u16*)take(96UL * 80 * 256 * 2);
  float* bsum = (float*)take(96UL * 80 * 4);
  // stream-ordered aliases
  float* ctx8 = (float*)xb;  // [8][96][64][256] f32 == 50.33 MB exactly
  u16* attn = kb;            // 50.33 MB

  cvt_all<<<26896, 256, 0, stream>>>(x, w_qkv, w_proj, proj, xb, wqkvb, wprojb, projb, mk);
  k0_qkv<<<dim3(18, 256), 256, 0, stream>>>(xb, wqkvb, qb, kb, vT);
  k2_k1<<<dim3(64, 96), 256, 0, stream>>>(kb, projb, mk);
  k3f<<<dim3(8, 96), 256, 0, stream>>>(kb, vT, projb, mk, ctx8, kpart);
  k3b<<<dim3(96, 5), 256, 0, stream>>>(ctx8, kpart, baug, bsum);
  k2q5<<<dim3(16, 96), 256, 0, stream>>>(qb, projb, baug, bsum, attn);
  k6_proj<<<dim3(6, 256), 256, 0, stream>>>(attn, wprojb, b_proj, out);
}

// Round 13
// 455.936 us; speedup vs baseline: 1.3331x; 1.0902x over previous
//
#include <hip/hip_runtime.h>
#include <hip/hip_bf16.h>

typedef __attribute__((ext_vector_type(4))) float f32x4;
typedef __attribute__((ext_vector_type(8))) short s16x8;
typedef __attribute__((ext_vector_type(4))) float f4v;
typedef __attribute__((ext_vector_type(4))) unsigned short us4;
typedef unsigned short u16;
typedef unsigned int u32;

#define H_ 12
#define NTOK 4096
#define DHEAD 64
#define MFEAT 256
#define CDIM 768

#define NORMALIZER 0.35355339059327373f  /* 64^-0.25 */
#define DIAGSCALE 0.0625f                /* 0.5 * NORMALIZER^2 */
#define RATIO_ 0.0625f                   /* 256^-0.5 */
#define EPS_ 1e-4f
#define DEFER_THR 4.0f                   /* defer-max threshold (normalized units) */

#define MFMA(a, b, c) __builtin_amdgcn_mfma_f32_16x16x32_bf16((a), (b), (c), 0, 0, 0)

__device__ __forceinline__ float bf2f(u16 u) {
  union { float f; u32 v; } x; x.v = ((u32)u) << 16; return x.f;
}
__device__ __forceinline__ u16 f2bf(float f) {
  union { float f; u32 v; } x; x.f = f;
  u32 v = x.v + 0x7FFFu + ((x.v >> 16) & 1u);
  return (u16)(v >> 16);
}
__device__ __forceinline__ u32 fenc(float f) {
  u32 u = __float_as_uint(f);
  return (u & 0x80000000u) ? ~u : (u | 0x80000000u);
}
__device__ __forceinline__ float fdec(u32 k) {
  u32 u = (k & 0x80000000u) ? (k & 0x7fffffffu) : ~k;
  return __uint_as_float(u);
}
__device__ __forceinline__ void glds16(const u16* g, u16* l) {
  __builtin_amdgcn_global_load_lds((const __attribute__((address_space(1))) void*)g,
                                   (__attribute__((address_space(3))) void*)l, 16, 0, 0);
}

// write a wave's staged 64x64 bf16 tile (rows padded to 72) to dst
__device__ __forceinline__ void st_write64(const u16* stw, u16* dst, long ld, int lane) {
  int r0 = lane >> 3, cc = lane & 7;
#pragma unroll
  for (int c = 0; c < 8; ++c) {
    int row = c * 8 + r0;
    s16x8 v = *(const s16x8*)(stw + row * 72 + cc * 8);
    *(s16x8*)(dst + (long)row * ld + cc * 8) = v;
  }
}

// ---------------- fused init + fp32->bf16 converts (block-aligned segments) ----------------
__global__ void cvt_all(const float* __restrict__ x, const float* __restrict__ wq,
                        const float* __restrict__ wp, const float* __restrict__ pj,
                        u16* __restrict__ xb, u16* __restrict__ wqb,
                        u16* __restrict__ wpb, u16* __restrict__ pjb, u32* __restrict__ mk) {
  int b = blockIdx.x;
  if (b == 0 && threadIdx.x < 8) mk[threadIdx.x] = 0u;
  const float* s;
  u16* d;
  int base;
  if (b < 24576)      { s = x;  d = xb;  base = b; }
  else if (b < 26304) { s = wq; d = wqb; base = b - 24576; }
  else if (b < 26880) { s = wp; d = wpb; base = b - 26304; }
  else                { s = pj; d = pjb; base = b - 26880; }
  long i = (long)base * 256 + threadIdx.x;
  f4v v = *(const f4v*)(s + i * 4);
  us4 o;
#pragma unroll
  for (int j = 0; j < 4; ++j) o[j] = f2bf(v[j]);
  *(us4*)(d + i * 4) = o;
}

// ---------------- K0: QKV GEMM + fused k-dash global max (BK=64 glds16, XCD groups) ----------------
__global__ __launch_bounds__(256) void k0_qkv(const u16* __restrict__ A, const u16* __restrict__ Bm,
                                              const u16* __restrict__ projb,
                                              u16* __restrict__ qb, u16* __restrict__ kb,
                                              u16* __restrict__ vT, u32* __restrict__ mk) {
  __shared__ u16 smem[4 * 64 * 72];   // loop: lA[0,8192) lB[8192,16384) u16; epilogue: 4x 64x72
  u16* lA = smem;
  u16* lB = smem + 8192;
  int tid = threadIdx.x, lane = tid & 63, wid = tid >> 6;
  // XCD-concentration remap (bijective on [0,4608))
  int p = blockIdx.x + blockIdx.y * 18;
  int r8 = p & 7, q = p >> 3;        // q in [0,576)
  int bx = q % 18;                   // N-panel member
  int by = (q / 18) * 8 + r8;        // M-panel group (same XCD for all 18 members)
  int m0 = by << 7, n0 = bx << 7;
  int wr = (wid >> 1) << 6, wc = (wid & 1) << 6;
  int l15 = lane & 15, lk = lane >> 4;
  int lr = lane >> 3;            // row within 8-row group
  int lu = (lane & 7) ^ lr;      // pre-swizzled source 16B-unit
  const u16* Ab = A + (long)m0 * CDIM;
  const u16* Bb = Bm + (long)n0 * CDIM;
  const u16* gA = Ab + (long)(wid * 32 + lr) * CDIM + lu * 8;
  const u16* gB = Bb + (long)(wid * 32 + lr) * CDIM + lu * 8;
  u16* dA = lA + wid * 2048;
  u16* dB = lB + wid * 2048;
  f32x4 acc[4][4];
#pragma unroll
  for (int i = 0; i < 4; ++i)
#pragma unroll
    for (int j = 0; j < 4; ++j) acc[i][j] = (f32x4){0.f, 0.f, 0.f, 0.f};
  for (int k0 = 0; k0 < CDIM; k0 += 64) {
    __syncthreads();
#pragma unroll
    for (int g = 0; g < 4; ++g) {
      glds16(gA + k0 + (long)g * 8 * CDIM, dA + g * 512);
      glds16(gB + k0 + (long)g * 8 * CDIM, dB + g * 512);
    }
    __syncthreads();
#pragma unroll
    for (int ks = 0; ks < 2; ++ks) {
      s16x8 af[4], bv[4];
#pragma unroll
      for (int i = 0; i < 4; ++i) {
        int co = ((ks * 4 + lk) ^ (l15 & 7)) * 8;   // swizzled read unit
        af[i] = *(const s16x8*)(lA + (wr + i * 16 + l15) * 64 + co);
        bv[i] = *(const s16x8*)(lB + (wc + i * 16 + l15) * 64 + co);
      }
#pragma unroll
      for (int i = 0; i < 4; ++i)
#pragma unroll
        for (int j = 0; j < 4; ++j) acc[i][j] = MFMA(af[i], bv[j], acc[i][j]);
    }
  }
  __syncthreads();  // before reusing smem as epilogue stage
  int colbase = n0 + wc;
  int qi = colbase / CDIM;
  int h = (colbase % CDIM) >> 6;
  int rowbase = m0 + wr;
  int b = rowbase >> 12;
  int nloc = rowbase & (NTOK - 1);
  u16* stw = smem + wid * 4608;
  if (qi < 2) {
#pragma unroll
    for (int i = 0; i < 4; ++i)
#pragma unroll
      for (int j = 0; j < 4; ++j)
#pragma unroll
        for (int r = 0; r < 4; ++r)
          stw[(i * 16 + lk * 4 + r) * 72 + j * 16 + l15] = f2bf(acc[i][j][r]);
    u16* dst = (qi == 0 ? qb : kb) + ((long)(b * H_ + h) * NTOK + nloc) * DHEAD;
    st_write64(stw, dst, DHEAD, lane);
    if (qi == 1) {
      // fused dash-max: dash = ktile(64x64, in stw) @ projb^T; only max is needed.
      float wm = -3.4e38f;
#pragma unroll
      for (int jc = 0; jc < 8; ++jc) {  // 8 feature-chunks of 32
        s16x8 af2[4][2], bv2[2][2];
#pragma unroll
        for (int ks = 0; ks < 2; ++ks) {
#pragma unroll
          for (int i = 0; i < 4; ++i)
            af2[i][ks] = *(const s16x8*)(stw + (i * 16 + l15) * 72 + ks * 32 + lk * 8);
#pragma unroll
          for (int j2 = 0; j2 < 2; ++j2)
            bv2[j2][ks] = *(const s16x8*)(projb + (long)(jc * 32 + j2 * 16 + l15) * DHEAD + ks * 32 + lk * 8);
        }
        f32x4 dacc[4][2];
#pragma unroll
        for (int i = 0; i < 4; ++i)
#pragma unroll
          for (int j2 = 0; j2 < 2; ++j2) dacc[i][j2] = (f32x4){0.f, 0.f, 0.f, 0.f};
#pragma unroll
        for (int ks = 0; ks < 2; ++ks)
#pragma unroll
          for (int i = 0; i < 4; ++i)
#pragma unroll
            for (int j2 = 0; j2 < 2; ++j2)
              dacc[i][j2] = MFMA(af2[i][ks], bv2[j2][ks], dacc[i][j2]);
#pragma unroll
        for (int i = 0; i < 4; ++i)
#pragma unroll
          for (int j2 = 0; j2 < 2; ++j2)
#pragma unroll
            for (int r = 0; r < 4; ++r) wm = fmaxf(wm, dacc[i][j2][r]);
      }
      wm = fmaxf(wm, __shfl_xor(wm, 1));
      wm = fmaxf(wm, __shfl_xor(wm, 2));
      wm = fmaxf(wm, __shfl_xor(wm, 4));
      wm = fmaxf(wm, __shfl_xor(wm, 8));
      wm = fmaxf(wm, __shfl_xor(wm, 16));
      wm = fmaxf(wm, __shfl_xor(wm, 32));
      if (lane == 0) atomicMax(mk + b, fenc(wm * NORMALIZER));
    }
  } else {
    // transposed stage: st[dd][n] (pack 4 r's into one b64)
#pragma unroll
    for (int i = 0; i < 4; ++i)
#pragma unroll
      for (int j = 0; j < 4; ++j) {
        us4 w;
#pragma unroll
        for (int r = 0; r < 4; ++r) w[r] = f2bf(acc[i][j][r]);
        *(us4*)(stw + (j * 16 + l15) * 72 + i * 16 + lk * 4) = w;
      }
    u16* dst = vT + (long)(b * H_ + h) * DHEAD * NTOK + nloc;
    st_write64(stw, dst, NTOK, lane);
  }
}

// ---------------- K3f: fused phi(k) + context = k'^T @ v (512-token chunk, barrier-free) ----------------
// ctx8 layout: [nc][bh][dd][m]  (dd-major, coalesced for k3b)
__global__ __launch_bounds__(256) void k3f(const u16* __restrict__ kb, const u16* __restrict__ vT,
                                           const u16* __restrict__ projb, const u32* __restrict__ mk,
                                           float* __restrict__ ctx8, float* __restrict__ kpart) {
  __shared__ u16 smem[4 * 64 * 72];
  int bh = blockIdx.y, nc = blockIdx.x;  // nc in [0,8)
  int tid = threadIdx.x, lane = tid & 63, wid = tid >> 6;
  int l15 = lane & 15, lk = lane >> 4;
  int wc = wid << 6;
  float mg = fdec(mk[bh / H_]);
  const u16* Kb = kb + ((long)bh * NTOK + nc * 512) * DHEAD;
  const u16* Vb = vT + (long)bh * DHEAD * NTOK + nc * 512;
  u16* ktw = smem + wid * 4608;  // per-wave 9216B tile (wave-local!)
  f32x4 ctxa[4][4];
#pragma unroll
  for (int i = 0; i < 4; ++i)
#pragma unroll
    for (int j = 0; j < 4; ++j) ctxa[i][j] = (f32x4){0.f, 0.f, 0.f, 0.f};
  float cs[4] = {0.f, 0.f, 0.f, 0.f};
  for (int sb = 0; sb < 8; ++sb) {
    const u16* Ksb = Kb + sb * 64 * DHEAD;
    s16x8 a[4][2];
    float ss[4] = {0.f, 0.f, 0.f, 0.f};
#pragma unroll
    for (int i = 0; i < 4; ++i)
#pragma unroll
      for (int ks = 0; ks < 2; ++ks) {
        a[i][ks] = *(const s16x8*)(Ksb + (long)(i * 16 + l15) * DHEAD + ks * 32 + lk * 8);
#pragma unroll
        for (int e = 0; e < 8; ++e) { float f = bf2f((u16)a[i][ks][e]); ss[i] += f * f; }
      }
    float dgv[4];
#pragma unroll
    for (int i = 0; i < 4; ++i) {
      float s = ss[i];
      s += __shfl_xor(s, 16);
      s += __shfl_xor(s, 32);
      dgv[i] = s * DIAGSCALE;  // diag of token 16i+l15 (uniform over lk)
    }
    f32x4 dacc[4][4];
#pragma unroll
    for (int i = 0; i < 4; ++i)
#pragma unroll
      for (int j = 0; j < 4; ++j) dacc[i][j] = (f32x4){0.f, 0.f, 0.f, 0.f};
    __builtin_amdgcn_s_setprio(1);
#pragma unroll
    for (int ks = 0; ks < 2; ++ks)
#pragma unroll
      for (int j = 0; j < 4; ++j) {
        s16x8 pb = *(const s16x8*)(projb + (long)(wc + j * 16 + l15) * DHEAD + ks * 32 + lk * 8);
#pragma unroll
        for (int i = 0; i < 4; ++i) dacc[i][j] = MFMA(a[i][ks], pb, dacc[i][j]);
      }
    __builtin_amdgcn_s_setprio(0);
    // diag at token 16i+4lk+r via shuffle
    float dgr[4][4];
#pragma unroll
    for (int i = 0; i < 4; ++i)
#pragma unroll
      for (int r = 0; r < 4; ++r) dgr[i][r] = __shfl(dgv[i], 4 * lk + r);
    // phi -> kT (wave-local), packed b64 writes
#pragma unroll
    for (int i = 0; i < 4; ++i)
#pragma unroll
      for (int j = 0; j < 4; ++j) {
        us4 w;
#pragma unroll
        for (int r = 0; r < 4; ++r) {
          float v = RATIO_ * (__expf(dacc[i][j][r] * NORMALIZER - dgr[i][r] - mg) + EPS_);
          cs[j] += v;
          w[r] = f2bf(v);
        }
        *(us4*)(ktw + (j * 16 + l15) * 72 + i * 16 + lk * 4) = w;
      }
    // context MFMA: A = k'(features) rows from ktw, B = vT rows
    __builtin_amdgcn_s_setprio(1);
#pragma unroll
    for (int ks = 0; ks < 2; ++ks) {
      s16x8 a2f[4], vb[4];
#pragma unroll
      for (int ii = 0; ii < 4; ++ii)
        a2f[ii] = *(const s16x8*)(ktw + (ii * 16 + l15) * 72 + ks * 32 + lk * 8);
#pragma unroll
      for (int jv = 0; jv < 4; ++jv)
        vb[jv] = *(const s16x8*)(Vb + (long)(jv * 16 + l15) * NTOK + sb * 64 + ks * 32 + lk * 8);
#pragma unroll
      for (int ii = 0; ii < 4; ++ii)
#pragma unroll
        for (int jv = 0; jv < 4; ++jv) ctxa[ii][jv] = MFMA(a2f[ii], vb[jv], ctxa[ii][jv]);
    }
    __builtin_amdgcn_s_setprio(0);
  }
  asm volatile("" ::: "memory");  // fence u16/f32 LDS type-pun reordering
  // epilogue: transpose wave quadrant to [dd][m] via LDS (stride 68 f32), coalesced f32 writes
  float* lf = (float*)ktw;  // 32 x 68 f32 = 8704B <= 9216B
  float* dstb = ctx8 + (long)(nc * 96 + bh) * (MFEAT * DHEAD);
#pragma unroll
  for (int half = 0; half < 2; ++half) {
#pragma unroll
    for (int jh = 0; jh < 2; ++jh) {
      int jv = half * 2 + jh;
#pragma unroll
      for (int ii = 0; ii < 4; ++ii)
        *(f4v*)(lf + (jh * 16 + l15) * 68 + ii * 16 + lk * 4) =
            (f4v){ctxa[ii][jv][0], ctxa[ii][jv][1], ctxa[ii][jv][2], ctxa[ii][jv][3]};
    }
#pragma unroll
    for (int u = 0; u < 8; ++u) {
      int dd_l = u * 4 + lk;
      f4v v = *(const f4v*)(lf + dd_l * 68 + l15 * 4);
      *(f4v*)(dstb + (long)(half * 32 + dd_l) * MFEAT + wc + l15 * 4) = v;
    }
    asm volatile("" ::: "memory");
  }
#pragma unroll
  for (int j = 0; j < 4; ++j) {
    float s = cs[j];
    s += __shfl_xor(s, 16);
    s += __shfl_xor(s, 32);
    if (lk == 0) kpart[((long)bh * 8 + nc) * MFEAT + wc + j * 16 + l15] = s;
  }
}

// ---------------- K3b: Baug[bh][80][256] = [ctx^T ; k_sum ; 0] + f32 row-sums bsum[bh][80] ----------------
__global__ __launch_bounds__(256) void k3b(const float* __restrict__ ctx8, const float* __restrict__ kpart,
                                           u16* __restrict__ baug, float* __restrict__ bsum) {
  int bh = blockIdx.x, y = blockIdx.y;
  int tid = threadIdx.x;
  u16* o = baug + (long)bh * 80 * MFEAT;
  if (y < 4) {
    int dd = y * 16 + (tid >> 4);
    int m0 = (tid & 15) * 16;
    f4v s[4];
#pragma unroll
    for (int e = 0; e < 4; ++e) s[e] = (f4v){0.f, 0.f, 0.f, 0.f};
    for (int c = 0; c < 8; ++c) {
      const float* r = ctx8 + (long)(c * 96 + bh) * (MFEAT * DHEAD) + dd * MFEAT + m0;
#pragma unroll
      for (int e = 0; e < 4; ++e) s[e] += *(const f4v*)(r + e * 4);
    }
    float t = 0.f;
#pragma unroll
    for (int e = 0; e < 4; ++e) {
      us4 w;
#pragma unroll
      for (int q = 0; q < 4; ++q) { t += s[e][q]; w[q] = f2bf(s[e][q]); }
      *(us4*)(o + dd * MFEAT + m0 + e * 4) = w;
    }
    t += __shfl_xor(t, 1); t += __shfl_xor(t, 2); t += __shfl_xor(t, 4); t += __shfl_xor(t, 8);
    if ((tid & 15) == 0) bsum[bh * 80 + dd] = t;
  } else {
    __shared__ float red[4];
    int m = tid;
    float ks = 0.f;
    for (int c = 0; c < 8; ++c) ks += kpart[((long)bh * 8 + c) * MFEAT + m];
    o[64 * MFEAT + m] = f2bf(ks);
    float t = ks;
    t += __shfl_xor(t, 1); t += __shfl_xor(t, 2); t += __shfl_xor(t, 4);
    t += __shfl_xor(t, 8); t += __shfl_xor(t, 16); t += __shfl_xor(t, 32);
    if ((m & 63) == 0) red[m >> 6] = t;
    __syncthreads();
    if (m == 0) bsum[bh * 80 + 64] = red[0] + red[1] + red[2] + red[3];
    for (int dd = 65; dd < 80; ++dd) o[dd * MFEAT + m] = 0;
    if (m < 15) bsum[bh * 80 + 65 + m] = 0.f;
  }
}

// ---------------- K2Q5: fused phi(q) + (q' @ Baug^T), defer-max (T13-exact), analytic eps ----------------
__global__ __launch_bounds__(256) void k2q5(const u16* __restrict__ qb, const u16* __restrict__ projb,
                                            const u16* __restrict__ baug, const float* __restrict__ bsum,
                                            u16* __restrict__ attn) {
  __shared__ u16 smem[4 * 64 * 72];
  int bh = blockIdx.y;
  int b = bh / H_, h = bh % H_;
  int tid = threadIdx.x, lane = tid & 63, wid = tid >> 6;
  int l15 = lane & 15, lk = lane >> 4;
  int tb = blockIdx.x * 256 + wid * 64;  // wave's 64 tokens
  const u16* Aq = qb + ((long)bh * NTOK + tb) * DHEAD;
  const u16* Bb = baug + (long)bh * 80 * MFEAT;
  u16* qTw = smem + wid * 4608;  // loop: [64 tok][40]; epilogue: [64][72]

  // resident q fragments + diag (token = 16i+l15)
  s16x8 a2[4][2];
  float ssv[4] = {0.f, 0.f, 0.f, 0.f};
#pragma unroll
  for (int i = 0; i < 4; ++i)
#pragma unroll
    for (int ks = 0; ks < 2; ++ks) {
      a2[i][ks] = *(const s16x8*)(Aq + (long)(i * 16 + l15) * DHEAD + ks * 32 + lk * 8);
#pragma unroll
      for (int e = 0; e < 8; ++e) { float f = bf2f((u16)a2[i][ks][e]); ssv[i] += f * f; }
    }
  float dgv[4];
#pragma unroll
  for (int i = 0; i < 4; ++i) {
    float s = ssv[i];
    s += __shfl_xor(s, 16);
    s += __shfl_xor(s, 32);
    dgv[i] = s * DIAGSCALE;
  }
  float rm[4] = {-3.4e38f, -3.4e38f, -3.4e38f, -3.4e38f};  // deferred (applied) max
  float tm[4] = {-3.4e38f, -3.4e38f, -3.4e38f, -3.4e38f};  // true running max
  f32x4 oacc[5][4];  // [baug-frag jo][token-frag i]; row=16jo+4lk+r, col(token)=16i+l15
#pragma unroll
  for (int jo = 0; jo < 5; ++jo)
#pragma unroll
    for (int i = 0; i < 4; ++i) oacc[jo][i] = (f32x4){0.f, 0.f, 0.f, 0.f};

  for (int c = 0; c < 8; ++c) {  // 32-feature chunks
    s16x8 pb[2][2];
#pragma unroll
    for (int j = 0; j < 2; ++j)
#pragma unroll
      for (int ks = 0; ks < 2; ++ks)
        pb[j][ks] = *(const s16x8*)(projb + (long)(c * 32 + j * 16 + l15) * DHEAD + ks * 32 + lk * 8);
    f32x4 dacc[2][4];
#pragma unroll
    for (int j = 0; j < 2; ++j)
#pragma unroll
      for (int i = 0; i < 4; ++i) dacc[j][i] = (f32x4){0.f, 0.f, 0.f, 0.f};
    __builtin_amdgcn_s_setprio(1);
#pragma unroll
    for (int ks = 0; ks < 2; ++ks)
#pragma unroll
      for (int j = 0; j < 2; ++j)
#pragma unroll
        for (int i = 0; i < 4; ++i) dacc[j][i] = MFMA(pb[j][ks], a2[i][ks], dacc[j][i]);
    __builtin_amdgcn_s_setprio(0);
#pragma unroll
    for (int i = 0; i < 4; ++i) {
      float cm = dacc[0][i][0];
      cm = fmaxf(cm, dacc[0][i][1]); cm = fmaxf(cm, dacc[0][i][2]); cm = fmaxf(cm, dacc[0][i][3]);
      cm = fmaxf(cm, dacc[1][i][0]); cm = fmaxf(cm, dacc[1][i][1]);
      cm = fmaxf(cm, dacc[1][i][2]); cm = fmaxf(cm, dacc[1][i][3]);
      cm = fmaxf(cm, __shfl_xor(cm, 16));
      cm = fmaxf(cm, __shfl_xor(cm, 32));
      tm[i] = fmaxf(tm[i], cm);
      // defer-max: only rescale when some token exceeds threshold (wave-uniform branch)
      if (__any((cm - rm[i]) * NORMALIZER > DEFER_THR)) {
        float rn = fmaxf(rm[i], cm);
        float fsc = __expf((rm[i] - rn) * NORMALIZER);
#pragma unroll
        for (int jo = 0; jo < 5; ++jo) oacc[jo][i] *= fsc;
        rm[i] = rn;
      }
    }
    // phi (NO eps -- handled analytically with lambda) -> wave-local LDS [64 tok][40]
#pragma unroll
    for (int i = 0; i < 4; ++i) {
      float dm = dgv[i] + rm[i] * NORMALIZER;
#pragma unroll
      for (int j = 0; j < 2; ++j) {
        us4 w;
#pragma unroll
        for (int r = 0; r < 4; ++r)
          w[r] = f2bf(RATIO_ * __expf(dacc[j][i][r] * NORMALIZER - dm));
        *(us4*)(qTw + (i * 16 + l15) * 40 + j * 16 + lk * 4) = w;
      }
    }
    s16x8 bB[5], qf[4];
#pragma unroll
    for (int jo = 0; jo < 5; ++jo)
      bB[jo] = *(const s16x8*)(Bb + (long)(jo * 16 + l15) * MFEAT + c * 32 + lk * 8);
#pragma unroll
    for (int i = 0; i < 4; ++i)
      qf[i] = *(const s16x8*)(qTw + (i * 16 + l15) * 40 + lk * 8);
    __builtin_amdgcn_s_setprio(1);
#pragma unroll
    for (int jo = 0; jo < 5; ++jo)
#pragma unroll
      for (int i = 0; i < 4; ++i) oacc[jo][i] = MFMA(bB[jo], qf[i], oacc[jo][i]);
    __builtin_amdgcn_s_setprio(0);
  }
  // analytic eps term with lambda correction: our accum = lam*(ref_GEMM - eps part),
  // so adding lam*ratio*eps*bsum makes the final ratio EXACTLY the reference value.
  float lamv[4];
#pragma unroll
  for (int i = 0; i < 4; ++i) lamv[i] = __expf((tm[i] - rm[i]) * NORMALIZER);
#pragma unroll
  for (int jo = 0; jo < 5; ++jo) {
    f4v bs = *(const f4v*)(bsum + (long)bh * 80 + jo * 16 + lk * 4);
#pragma unroll
    for (int i = 0; i < 4; ++i)
#pragma unroll
      for (int r = 0; r < 4; ++r) oacc[jo][i][r] += (RATIO_ * EPS_) * bs[r] * lamv[i];
  }
  // epilogue: divide by denominator, stage, write
  u16* stw = qTw;  // stride 72 now
#pragma unroll
  for (int i = 0; i < 4; ++i) {
    float dn = __shfl(oacc[4][i][0], l15);  // token 16i+l15's denom from lane (l15, lk=0)
    float inv = 1.0f / dn;
#pragma unroll
    for (int jo = 0; jo < 4; ++jo) {
      us4 w;
#pragma unroll
      for (int r = 0; r < 4; ++r) w[r] = f2bf(oacc[jo][i][r] * inv);
      *(us4*)(stw + (i * 16 + l15) * 72 + jo * 16 + lk * 4) = w;
    }
  }
  u16* dst = attn + ((long)b * NTOK + tb) * CDIM + h * DHEAD;
  st_write64(stw, dst, CDIM, lane);
}

// ---------------- K6: out = attn @ w_proj^T + b_proj (BK=64, XCD-concentrated, fp32 out) ----------------
__global__ __launch_bounds__(256) void k6_proj(const u16* __restrict__ A, const u16* __restrict__ Bm,
                                               const float* __restrict__ bproj, float* __restrict__ out) {
  __shared__ u16 smem[16384];  // lA[0,8192) lB[8192,16384)
  u16* lA = smem;
  u16* lB = smem + 8192;
  int tid = threadIdx.x, lane = tid & 63, wid = tid >> 6;
  // XCD-concentration remap (bijective on [0,1536))
  int p = blockIdx.x + blockIdx.y * 6;
  int r8 = p & 7, q = p >> 3;        // q in [0,192)
  int bx = q % 6;
  int by = (q / 6) * 8 + r8;
  int m0 = by << 7, n0 = bx << 7;
  int wr = (wid >> 1) << 6, wc = (wid & 1) << 6;
  int l15 = lane & 15, lk = lane >> 4;
  int lr = lane >> 3;
  int lu = (lane & 7) ^ lr;
  const u16* Ab = A + (long)m0 * CDIM;
  const u16* Bb = Bm + (long)n0 * CDIM;
  const u16* gA = Ab + (long)(wid * 32 + lr) * CDIM + lu * 8;
  const u16* gB = Bb + (long)(wid * 32 + lr) * CDIM + lu * 8;
  u16* dA = lA + wid * 2048;
  u16* dB = lB + wid * 2048;
  f32x4 acc[4][4];
#pragma unroll
  for (int i = 0; i < 4; ++i)
#pragma unroll
    for (int j = 0; j < 4; ++j) acc[i][j] = (f32x4){0.f, 0.f, 0.f, 0.f};
  for (int k0 = 0; k0 < CDIM; k0 += 64) {
    __syncthreads();
#pragma unroll
    for (int g = 0; g < 4; ++g) {
      glds16(gA + k0 + (long)g * 8 * CDIM, dA + g * 512);
      glds16(gB + k0 + (long)g * 8 * CDIM, dB + g * 512);
    }
    __syncthreads();
#pragma unroll
    for (int ks = 0; ks < 2; ++ks) {
      s16x8 af[4], bv[4];
#pragma unroll
      for (int i = 0; i < 4; ++i) {
        int co = ((ks * 4 + lk) ^ (l15 & 7)) * 8;
        af[i] = *(const s16x8*)(lA + (wr + i * 16 + l15) * 64 + co);
        bv[i] = *(const s16x8*)(lB + (wc + i * 16 + l15) * 64 + co);
      }
#pragma unroll
      for (int i = 0; i < 4; ++i)
#pragma unroll
        for (int j = 0; j < 4; ++j) acc[i][j] = MFMA(af[i], bv[j], acc[i][j]);
    }
  }
  float bpv[4];
#pragma unroll
  for (int j = 0; j < 4; ++j) bpv[j] = bproj[n0 + wc + j * 16 + l15];
#pragma unroll
  for (int i = 0; i < 4; ++i)
#pragma unroll
    for (int j = 0; j < 4; ++j)
#pragma unroll
      for (int r = 0; r < 4; ++r) {
        long row = m0 + wr + i * 16 + lk * 4 + r;
        int col = n0 + wc + j * 16 + l15;
        out[row * CDIM + col] = acc[i][j][r] + bpv[j];
      }
}

extern "C" void kernel_launch(void* const* d_in, const int* in_sizes, int n_in,
                              void* d_out, int out_size, void* d_ws, size_t ws_size,
                              hipStream_t stream) {
  const float* x = (const float*)d_in[0];
  const float* w_qkv = (const float*)d_in[1];
  const float* w_proj = (const float*)d_in[2];
  const float* b_proj = (const float*)d_in[3];
  const float* proj = (const float*)d_in[4];
  float* out = (float*)d_out;

  char* p = (char*)d_ws;
  auto take = [&](size_t bytes) {
    char* r = p;
    p += (bytes + 255) & ~(size_t)255;
    return r;
  };
  u16* xb = (u16*)take(32768UL * 768 * 2);      // 50.33 MB; dead after k0 -> ctx8
  u16* wqkvb = (u16*)take(2304UL * 768 * 2);
  u16* wprojb = (u16*)take(768UL * 768 * 2);
  u16* projb = (u16*)take(256UL * 64 * 2);
  u16* qb = (u16*)take(96UL * 4096 * 64 * 2);   // 50.33 MB
  u16* kb = (u16*)take(96UL * 4096 * 64 * 2);   // 50.33 MB; dead after k3f -> attn
  u16* vT = (u16*)take(96UL * 64 * 4096 * 2);   // 50.33 MB
  float* kpart = (float*)take(96UL * 8 * 256 * 4);
  u32* mk = (u32*)take(256);
  u16* baug = (u16*)take(96UL * 80 * 256 * 2);
  float* bsum = (float*)take(96UL * 80 * 4);
  // stream-ordered aliases
  float* ctx8 = (float*)xb;  // [8][96][64][256] f32 == 50.33 MB exactly
  u16* attn = kb;            // 50.33 MB

  cvt_all<<<26896, 256, 0, stream>>>(x, w_qkv, w_proj, proj, xb, wqkvb, wprojb, projb, mk);
  k0_qkv<<<dim3(18, 256), 256, 0, stream>>>(xb, wqkvb, projb, qb, kb, vT, mk);
  k3f<<<dim3(8, 96), 256, 0, stream>>>(kb, vT, projb, mk, ctx8, kpart);
  k3b<<<dim3(96, 5), 256, 0, stream>>>(ctx8, kpart, baug, bsum);
  k2q5<<<dim3(16, 96), 256, 0, stream>>>(qb, projb, baug, bsum, attn);
  k6_proj<<<dim3(6, 256), 256, 0, stream>>>(attn, wprojb, b_proj, out);
}

// Round 14
// 415.593 us; speedup vs baseline: 1.4625x; 1.0971x over previous
//
#include <hip/hip_runtime.h>
#include <hip/hip_bf16.h>

typedef __attribute__((ext_vector_type(4))) float f32x4;
typedef __attribute__((ext_vector_type(8))) short s16x8;
typedef __attribute__((ext_vector_type(4))) float f4v;
typedef __attribute__((ext_vector_type(4))) unsigned short us4;
typedef unsigned short u16;
typedef unsigned int u32;

#define H_ 12
#define NTOK 4096
#define DHEAD 64
#define MFEAT 256
#define CDIM 768

#define NORMALIZER 0.35355339059327373f  /* 64^-0.25 */
#define DIAGSCALE 0.0625f                /* 0.5 * NORMALIZER^2 */
#define RATIO_ 0.0625f                   /* 256^-0.5 */
#define EPS_ 1e-4f
#define DEFER_THR 4.0f                   /* defer-max threshold (normalized units) */

#define MFMA(a, b, c) __builtin_amdgcn_mfma_f32_16x16x32_bf16((a), (b), (c), 0, 0, 0)

__device__ __forceinline__ float bf2f(u16 u) {
  union { float f; u32 v; } x; x.v = ((u32)u) << 16; return x.f;
}
__device__ __forceinline__ u16 f2bf(float f) {
  union { float f; u32 v; } x; x.f = f;
  u32 v = x.v + 0x7FFFu + ((x.v >> 16) & 1u);
  return (u16)(v >> 16);
}
__device__ __forceinline__ void glds16(const u16* g, u16* l) {
  __builtin_amdgcn_global_load_lds((const __attribute__((address_space(1))) void*)g,
                                   (__attribute__((address_space(3))) void*)l, 16, 0, 0);
}

// write a wave's staged 64x64 bf16 tile (rows padded to 72) to dst
__device__ __forceinline__ void st_write64(const u16* stw, u16* dst, long ld, int lane) {
  int r0 = lane >> 3, cc = lane & 7;
#pragma unroll
  for (int c = 0; c < 8; ++c) {
    int row = c * 8 + r0;
    s16x8 v = *(const s16x8*)(stw + row * 72 + cc * 8);
    *(s16x8*)(dst + (long)row * ld + cc * 8) = v;
  }
}

// ---------------- fused fp32->bf16 converts (block-aligned segments) ----------------
__global__ void cvt_all(const float* __restrict__ x, const float* __restrict__ wq,
                        const float* __restrict__ wp, const float* __restrict__ pj,
                        u16* __restrict__ xb, u16* __restrict__ wqb,
                        u16* __restrict__ wpb, u16* __restrict__ pjb) {
  int b = blockIdx.x;
  const float* s;
  u16* d;
  int base;
  if (b < 24576)      { s = x;  d = xb;  base = b; }
  else if (b < 26304) { s = wq; d = wqb; base = b - 24576; }
  else if (b < 26880) { s = wp; d = wpb; base = b - 26304; }
  else                { s = pj; d = pjb; base = b - 26880; }
  long i = (long)base * 256 + threadIdx.x;
  f4v v = *(const f4v*)(s + i * 4);
  us4 o;
#pragma unroll
  for (int j = 0; j < 4; ++j) o[j] = f2bf(v[j]);
  *(us4*)(d + i * 4) = o;
}

// ---------------- K0: QKV GEMM, BK=64 glds16, XCD-concentrated (round-12 proven) ----------------
__global__ __launch_bounds__(256) void k0_qkv(const u16* __restrict__ A, const u16* __restrict__ Bm,
                                              u16* __restrict__ qb, u16* __restrict__ kb,
                                              u16* __restrict__ vT) {
  __shared__ u16 smem[4 * 64 * 72];   // loop: lA[0,8192) lB[8192,16384) u16; epilogue: 4x 64x72
  u16* lA = smem;
  u16* lB = smem + 8192;
  int tid = threadIdx.x, lane = tid & 63, wid = tid >> 6;
  // XCD-concentration remap (bijective on [0,4608))
  int p = blockIdx.x + blockIdx.y * 18;
  int r8 = p & 7, q = p >> 3;        // q in [0,576)
  int bx = q % 18;                   // N-panel member
  int by = (q / 18) * 8 + r8;        // M-panel group (same XCD for all 18 members)
  int m0 = by << 7, n0 = bx << 7;
  int wr = (wid >> 1) << 6, wc = (wid & 1) << 6;
  int l15 = lane & 15, lk = lane >> 4;
  int lr = lane >> 3;            // row within 8-row group
  int lu = (lane & 7) ^ lr;      // pre-swizzled source 16B-unit
  const u16* Ab = A + (long)m0 * CDIM;
  const u16* Bb = Bm + (long)n0 * CDIM;
  const u16* gA = Ab + (long)(wid * 32 + lr) * CDIM + lu * 8;
  const u16* gB = Bb + (long)(wid * 32 + lr) * CDIM + lu * 8;
  u16* dA = lA + wid * 2048;
  u16* dB = lB + wid * 2048;
  f32x4 acc[4][4];
#pragma unroll
  for (int i = 0; i < 4; ++i)
#pragma unroll
    for (int j = 0; j < 4; ++j) acc[i][j] = (f32x4){0.f, 0.f, 0.f, 0.f};
  for (int k0 = 0; k0 < CDIM; k0 += 64) {
    __syncthreads();
#pragma unroll
    for (int g = 0; g < 4; ++g) {
      glds16(gA + k0 + (long)g * 8 * CDIM, dA + g * 512);
      glds16(gB + k0 + (long)g * 8 * CDIM, dB + g * 512);
    }
    __syncthreads();
#pragma unroll
    for (int ks = 0; ks < 2; ++ks) {
      s16x8 af[4], bv[4];
#pragma unroll
      for (int i = 0; i < 4; ++i) {
        int co = ((ks * 4 + lk) ^ (l15 & 7)) * 8;   // swizzled read unit
        af[i] = *(const s16x8*)(lA + (wr + i * 16 + l15) * 64 + co);
        bv[i] = *(const s16x8*)(lB + (wc + i * 16 + l15) * 64 + co);
      }
#pragma unroll
      for (int i = 0; i < 4; ++i)
#pragma unroll
        for (int j = 0; j < 4; ++j) acc[i][j] = MFMA(af[i], bv[j], acc[i][j]);
    }
  }
  __syncthreads();  // before reusing smem as epilogue stage
  int colbase = n0 + wc;
  int qi = colbase / CDIM;
  int h = (colbase % CDIM) >> 6;
  int rowbase = m0 + wr;
  int b = rowbase >> 12;
  int nloc = rowbase & (NTOK - 1);
  u16* stw = smem + wid * 4608;
  if (qi < 2) {
#pragma unroll
    for (int i = 0; i < 4; ++i)
#pragma unroll
      for (int j = 0; j < 4; ++j)
#pragma unroll
        for (int r = 0; r < 4; ++r)
          stw[(i * 16 + lk * 4 + r) * 72 + j * 16 + l15] = f2bf(acc[i][j][r]);
    u16* dst = (qi == 0 ? qb : kb) + ((long)(b * H_ + h) * NTOK + nloc) * DHEAD;
    st_write64(stw, dst, DHEAD, lane);
  } else {
    // transposed stage: st[dd][n] (pack 4 r's into one b64)
#pragma unroll
    for (int i = 0; i < 4; ++i)
#pragma unroll
      for (int j = 0; j < 4; ++j) {
        us4 w;
#pragma unroll
        for (int r = 0; r < 4; ++r) w[r] = f2bf(acc[i][j][r]);
        *(us4*)(stw + (j * 16 + l15) * 72 + i * 16 + lk * 4) = w;
      }
    u16* dst = vT + (long)(b * H_ + h) * DHEAD * NTOK + nloc;
    st_write64(stw, dst, NTOK, lane);
  }
}

// ---------------- K3f: phi(k)+context with LOCAL deferred max (no global max pre-pass) ----------------
// Outputs (per wave = (bh,nc,wc)): ctxE = sum E*v (E = exp(dash*N - diag - rm*N)),
// csE = sum E per feature, tm (true max, raw), rm (applied max, raw); vsum (wave 0): sum v per dd.
__global__ __launch_bounds__(256) void k3f(const u16* __restrict__ kb, const u16* __restrict__ vT,
                                           const u16* __restrict__ projb,
                                           float* __restrict__ ctx8, float* __restrict__ kpart,
                                           float* __restrict__ tmbuf, float* __restrict__ rmbuf,
                                           float* __restrict__ vsumb) {
  __shared__ u16 smem[4 * 64 * 72];
  int bh = blockIdx.y, nc = blockIdx.x;  // nc in [0,8)
  int tid = threadIdx.x, lane = tid & 63, wid = tid >> 6;
  int l15 = lane & 15, lk = lane >> 4;
  int wc = wid << 6;
  const u16* Kb = kb + ((long)bh * NTOK + nc * 512) * DHEAD;
  const u16* Vb = vT + (long)bh * DHEAD * NTOK + nc * 512;
  u16* ktw = smem + wid * 4608;  // per-wave 9216B tile (wave-local!)
  f32x4 ctxa[4][4];
#pragma unroll
  for (int i = 0; i < 4; ++i)
#pragma unroll
    for (int j = 0; j < 4; ++j) ctxa[i][j] = (f32x4){0.f, 0.f, 0.f, 0.f};
  float cs[4] = {0.f, 0.f, 0.f, 0.f};
  float rm = -3.4e38f, tm = -3.4e38f;
  float vsacc[4] = {0.f, 0.f, 0.f, 0.f};  // wave 0 only
  for (int sb = 0; sb < 8; ++sb) {
    const u16* Ksb = Kb + sb * 64 * DHEAD;
    s16x8 a[4][2];
    float ss[4] = {0.f, 0.f, 0.f, 0.f};
#pragma unroll
    for (int i = 0; i < 4; ++i)
#pragma unroll
      for (int ks = 0; ks < 2; ++ks) {
        a[i][ks] = *(const s16x8*)(Ksb + (long)(i * 16 + l15) * DHEAD + ks * 32 + lk * 8);
#pragma unroll
        for (int e = 0; e < 8; ++e) { float f = bf2f((u16)a[i][ks][e]); ss[i] += f * f; }
      }
    float dgv[4];
#pragma unroll
    for (int i = 0; i < 4; ++i) {
      float s = ss[i];
      s += __shfl_xor(s, 16);
      s += __shfl_xor(s, 32);
      dgv[i] = s * DIAGSCALE;  // diag of token 16i+l15 (uniform over lk)
    }
    f32x4 dacc[4][4];
#pragma unroll
    for (int i = 0; i < 4; ++i)
#pragma unroll
      for (int j = 0; j < 4; ++j) dacc[i][j] = (f32x4){0.f, 0.f, 0.f, 0.f};
    __builtin_amdgcn_s_setprio(1);
#pragma unroll
    for (int ks = 0; ks < 2; ++ks)
#pragma unroll
      for (int j = 0; j < 4; ++j) {
        s16x8 pb = *(const s16x8*)(projb + (long)(wc + j * 16 + l15) * DHEAD + ks * 32 + lk * 8);
#pragma unroll
        for (int i = 0; i < 4; ++i) dacc[i][j] = MFMA(a[i][ks], pb, dacc[i][j]);
      }
    __builtin_amdgcn_s_setprio(0);
    // wave max of raw dash (reference max is over dash only, diag not subtracted)
    float cm = -3.4e38f;
#pragma unroll
    for (int i = 0; i < 4; ++i)
#pragma unroll
      for (int j = 0; j < 4; ++j)
#pragma unroll
        for (int r = 0; r < 4; ++r) cm = fmaxf(cm, dacc[i][j][r]);
    cm = fmaxf(cm, __shfl_xor(cm, 1));
    cm = fmaxf(cm, __shfl_xor(cm, 2));
    cm = fmaxf(cm, __shfl_xor(cm, 4));
    cm = fmaxf(cm, __shfl_xor(cm, 8));
    cm = fmaxf(cm, __shfl_xor(cm, 16));
    cm = fmaxf(cm, __shfl_xor(cm, 32));
    tm = fmaxf(tm, cm);
    if ((cm - rm) * NORMALIZER > DEFER_THR) {  // wave-uniform (cm uniform after reduce)
      float fsc = __expf((rm - cm) * NORMALIZER);  // 0 on first trigger (rm=-inf), accs are 0
#pragma unroll
      for (int ii = 0; ii < 4; ++ii)
#pragma unroll
        for (int jv = 0; jv < 4; ++jv) ctxa[ii][jv] *= fsc;
#pragma unroll
      for (int j = 0; j < 4; ++j) cs[j] *= fsc;
      rm = cm;
    }
    float rmN = rm * NORMALIZER;
    // diag at token 16i+4lk+r via shuffle
    float dgr[4][4];
#pragma unroll
    for (int i = 0; i < 4; ++i)
#pragma unroll
      for (int r = 0; r < 4; ++r) dgr[i][r] = __shfl(dgv[i], 4 * lk + r);
    // E -> kT (wave-local), packed b64 writes; E <= e^DEFER_THR
#pragma unroll
    for (int i = 0; i < 4; ++i)
#pragma unroll
      for (int j = 0; j < 4; ++j) {
        us4 w;
#pragma unroll
        for (int r = 0; r < 4; ++r) {
          float v = __expf(dacc[i][j][r] * NORMALIZER - dgr[i][r] - rmN);
          cs[j] += v;
          w[r] = f2bf(v);
        }
        *(us4*)(ktw + (j * 16 + l15) * 72 + i * 16 + lk * 4) = w;
      }
    // context MFMA: A = E(features) rows from ktw, B = vT rows; + vsum on wave 0
    __builtin_amdgcn_s_setprio(1);
#pragma unroll
    for (int ks = 0; ks < 2; ++ks) {
      s16x8 a2f[4], vb[4];
#pragma unroll
      for (int ii = 0; ii < 4; ++ii)
        a2f[ii] = *(const s16x8*)(ktw + (ii * 16 + l15) * 72 + ks * 32 + lk * 8);
#pragma unroll
      for (int jv = 0; jv < 4; ++jv)
        vb[jv] = *(const s16x8*)(Vb + (long)(jv * 16 + l15) * NTOK + sb * 64 + ks * 32 + lk * 8);
      if (wid == 0) {
#pragma unroll
        for (int jv = 0; jv < 4; ++jv)
#pragma unroll
          for (int e = 0; e < 8; ++e) vsacc[jv] += bf2f((u16)vb[jv][e]);
      }
#pragma unroll
      for (int ii = 0; ii < 4; ++ii)
#pragma unroll
        for (int jv = 0; jv < 4; ++jv) ctxa[ii][jv] = MFMA(a2f[ii], vb[jv], ctxa[ii][jv]);
    }
    __builtin_amdgcn_s_setprio(0);
  }
  asm volatile("" ::: "memory");  // fence u16/f32 LDS type-pun reordering
  // epilogue: transpose wave quadrant to [dd][m] via LDS (stride 68 f32), coalesced f32 writes
  float* lf = (float*)ktw;  // 32 x 68 f32 = 8704B <= 9216B
  float* dstb = ctx8 + (long)(nc * 96 + bh) * (MFEAT * DHEAD);
#pragma unroll
  for (int half = 0; half < 2; ++half) {
#pragma unroll
    for (int jh = 0; jh < 2; ++jh) {
      int jv = half * 2 + jh;
#pragma unroll
      for (int ii = 0; ii < 4; ++ii)
        *(f4v*)(lf + (jh * 16 + l15) * 68 + ii * 16 + lk * 4) =
            (f4v){ctxa[ii][jv][0], ctxa[ii][jv][1], ctxa[ii][jv][2], ctxa[ii][jv][3]};
    }
#pragma unroll
    for (int u = 0; u < 8; ++u) {
      int dd_l = u * 4 + lk;
      f4v v = *(const f4v*)(lf + dd_l * 68 + l15 * 4);
      *(f4v*)(dstb + (long)(half * 32 + dd_l) * MFEAT + wc + l15 * 4) = v;
    }
    asm volatile("" ::: "memory");
  }
#pragma unroll
  for (int j = 0; j < 4; ++j) {
    float s = cs[j];
    s += __shfl_xor(s, 16);
    s += __shfl_xor(s, 32);
    if (lk == 0) kpart[((long)bh * 8 + nc) * MFEAT + wc + j * 16 + l15] = s;
  }
  if (lane == 0) {
    tmbuf[bh * 32 + nc * 4 + wid] = tm;
    rmbuf[bh * 32 + nc * 4 + wid] = rm;
  }
  if (wid == 0) {
#pragma unroll
    for (int jv = 0; jv < 4; ++jv) {
      float s = vsacc[jv];
      s += __shfl_xor(s, 16);
      s += __shfl_xor(s, 32);
      if (lk == 0) vsumb[((long)bh * 8 + nc) * 64 + jv * 16 + l15] = s;
    }
  }
}

// ---------------- K3b: combine chunks with exact global max; Baug + bsum ----------------
__global__ __launch_bounds__(256) void k3b(const float* __restrict__ ctx8, const float* __restrict__ kpart,
                                           const float* __restrict__ tmbuf, const float* __restrict__ rmbuf,
                                           const float* __restrict__ vsumb,
                                           u16* __restrict__ baug, float* __restrict__ bsum) {
  __shared__ float red[4];
  __shared__ float mgs;
  int bh = blockIdx.x, y = blockIdx.y;
  int tid = threadIdx.x, lane = tid & 63, wid4 = tid >> 6;
  int b = bh / H_;
  // mg = exact global max for batch b (max of 384 per-wave true maxes)
  float ml = -3.4e38f;
  for (int i = tid; i < 384; i += 256) ml = fmaxf(ml, tmbuf[b * 384 + i]);
  ml = fmaxf(ml, __shfl_xor(ml, 1));
  ml = fmaxf(ml, __shfl_xor(ml, 2));
  ml = fmaxf(ml, __shfl_xor(ml, 4));
  ml = fmaxf(ml, __shfl_xor(ml, 8));
  ml = fmaxf(ml, __shfl_xor(ml, 16));
  ml = fmaxf(ml, __shfl_xor(ml, 32));
  if (lane == 0) red[wid4] = ml;
  __syncthreads();
  if (tid == 0) mgs = fmaxf(fmaxf(red[0], red[1]), fmaxf(red[2], red[3]));
  __syncthreads();
  float mg = mgs;
  u16* o = baug + (long)bh * 80 * MFEAT;
  if (y < 4) {
    int dd = y * 16 + (tid >> 4);
    int m0 = (tid & 15) * 16;
    int qd = m0 >> 6;
    float scale[8];
#pragma unroll
    for (int c = 0; c < 8; ++c)
      scale[c] = __expf((rmbuf[bh * 32 + c * 4 + qd] - mg) * NORMALIZER);
    f4v s[4];
#pragma unroll
    for (int e = 0; e < 4; ++e) s[e] = (f4v){0.f, 0.f, 0.f, 0.f};
    for (int c = 0; c < 8; ++c) {
      const float* r = ctx8 + (long)(c * 96 + bh) * (MFEAT * DHEAD) + dd * MFEAT + m0;
#pragma unroll
      for (int e = 0; e < 4; ++e) s[e] += scale[c] * (*(const f4v*)(r + e * 4));
    }
    float vs = 0.f;
#pragma unroll
    for (int c = 0; c < 8; ++c) vs += vsumb[((long)bh * 8 + c) * 64 + dd];
    float epsb = RATIO_ * EPS_ * vs;
    float t = 0.f;
#pragma unroll
    for (int e = 0; e < 4; ++e) {
      us4 w;
#pragma unroll
      for (int q = 0; q < 4; ++q) {
        float val = RATIO_ * s[e][q] + epsb;
        t += val;
        w[q] = f2bf(val);
      }
      *(us4*)(o + dd * MFEAT + m0 + e * 4) = w;
    }
    t += __shfl_xor(t, 1); t += __shfl_xor(t, 2); t += __shfl_xor(t, 4); t += __shfl_xor(t, 8);
    if ((tid & 15) == 0) bsum[bh * 80 + dd] = t;
  } else {
    int m = tid;
    int qd = m >> 6;
    float ks = 0.f;
#pragma unroll
    for (int c = 0; c < 8; ++c)
      ks += __expf((rmbuf[bh * 32 + c * 4 + qd] - mg) * NORMALIZER) * kpart[((long)bh * 8 + c) * MFEAT + m];
    ks = RATIO_ * ks + RATIO_ * EPS_ * 4096.0f;
    o[64 * MFEAT + m] = f2bf(ks);
    float t = ks;
    t += __shfl_xor(t, 1); t += __shfl_xor(t, 2); t += __shfl_xor(t, 4);
    t += __shfl_xor(t, 8); t += __shfl_xor(t, 16); t += __shfl_xor(t, 32);
    if ((m & 63) == 0) red[m >> 6] = t;
    __syncthreads();
    if (m == 0) bsum[bh * 80 + 64] = red[0] + red[1] + red[2] + red[3];
    for (int dd = 65; dd < 80; ++dd) o[dd * MFEAT + m] = 0;
    if (m < 15) bsum[bh * 80 + 65 + m] = 0.f;
  }
}

// ---------------- K2Q5: fused phi(q) + (q' @ Baug^T), defer-max (T13-exact), analytic eps ----------------
__global__ __launch_bounds__(256) void k2q5(const u16* __restrict__ qb, const u16* __restrict__ projb,
                                            const u16* __restrict__ baug, const float* __restrict__ bsum,
                                            u16* __restrict__ attn) {
  __shared__ u16 smem[4 * 64 * 72];
  int bh = blockIdx.y;
  int b = bh / H_, h = bh % H_;
  int tid = threadIdx.x, lane = tid & 63, wid = tid >> 6;
  int l15 = lane & 15, lk = lane >> 4;
  int tb = blockIdx.x * 256 + wid * 64;  // wave's 64 tokens
  const u16* Aq = qb + ((long)bh * NTOK + tb) * DHEAD;
  const u16* Bb = baug + (long)bh * 80 * MFEAT;
  u16* qTw = smem + wid * 4608;  // loop: [64 tok][40]; epilogue: [64][72]

  // resident q fragments + diag (token = 16i+l15)
  s16x8 a2[4][2];
  float ssv[4] = {0.f, 0.f, 0.f, 0.f};
#pragma unroll
  for (int i = 0; i < 4; ++i)
#pragma unroll
    for (int ks = 0; ks < 2; ++ks) {
      a2[i][ks] = *(const s16x8*)(Aq + (long)(i * 16 + l15) * DHEAD + ks * 32 + lk * 8);
#pragma unroll
      for (int e = 0; e < 8; ++e) { float f = bf2f((u16)a2[i][ks][e]); ssv[i] += f * f; }
    }
  float dgv[4];
#pragma unroll
  for (int i = 0; i < 4; ++i) {
    float s = ssv[i];
    s += __shfl_xor(s, 16);
    s += __shfl_xor(s, 32);
    dgv[i] = s * DIAGSCALE;
  }
  float rm[4] = {-3.4e38f, -3.4e38f, -3.4e38f, -3.4e38f};  // deferred (applied) max
  float tm[4] = {-3.4e38f, -3.4e38f, -3.4e38f, -3.4e38f};  // true running max
  f32x4 oacc[5][4];  // [baug-frag jo][token-frag i]; row=16jo+4lk+r, col(token)=16i+l15
#pragma unroll
  for (int jo = 0; jo < 5; ++jo)
#pragma unroll
    for (int i = 0; i < 4; ++i) oacc[jo][i] = (f32x4){0.f, 0.f, 0.f, 0.f};

  for (int c = 0; c < 8; ++c) {  // 32-feature chunks
    s16x8 pb[2][2];
#pragma unroll
    for (int j = 0; j < 2; ++j)
#pragma unroll
      for (int ks = 0; ks < 2; ++ks)
        pb[j][ks] = *(const s16x8*)(projb + (long)(c * 32 + j * 16 + l15) * DHEAD + ks * 32 + lk * 8);
    f32x4 dacc[2][4];
#pragma unroll
    for (int j = 0; j < 2; ++j)
#pragma unroll
      for (int i = 0; i < 4; ++i) dacc[j][i] = (f32x4){0.f, 0.f, 0.f, 0.f};
    __builtin_amdgcn_s_setprio(1);
#pragma unroll
    for (int ks = 0; ks < 2; ++ks)
#pragma unroll
      for (int j = 0; j < 2; ++j)
#pragma unroll
        for (int i = 0; i < 4; ++i) dacc[j][i] = MFMA(pb[j][ks], a2[i][ks], dacc[j][i]);
    __builtin_amdgcn_s_setprio(0);
#pragma unroll
    for (int i = 0; i < 4; ++i) {
      float cm = dacc[0][i][0];
      cm = fmaxf(cm, dacc[0][i][1]); cm = fmaxf(cm, dacc[0][i][2]); cm = fmaxf(cm, dacc[0][i][3]);
      cm = fmaxf(cm, dacc[1][i][0]); cm = fmaxf(cm, dacc[1][i][1]);
      cm = fmaxf(cm, dacc[1][i][2]); cm = fmaxf(cm, dacc[1][i][3]);
      cm = fmaxf(cm, __shfl_xor(cm, 16));
      cm = fmaxf(cm, __shfl_xor(cm, 32));
      tm[i] = fmaxf(tm[i], cm);
      if (__any((cm - rm[i]) * NORMALIZER > DEFER_THR)) {
        float rn = fmaxf(rm[i], cm);
        float fsc = __expf((rm[i] - rn) * NORMALIZER);
#pragma unroll
        for (int jo = 0; jo < 5; ++jo) oacc[jo][i] *= fsc;
        rm[i] = rn;
      }
    }
    // phi (NO eps -- handled analytically with lambda) -> wave-local LDS [64 tok][40]
#pragma unroll
    for (int i = 0; i < 4; ++i) {
      float dm = dgv[i] + rm[i] * NORMALIZER;
#pragma unroll
      for (int j = 0; j < 2; ++j) {
        us4 w;
#pragma unroll
        for (int r = 0; r < 4; ++r)
          w[r] = f2bf(RATIO_ * __expf(dacc[j][i][r] * NORMALIZER - dm));
        *(us4*)(qTw + (i * 16 + l15) * 40 + j * 16 + lk * 4) = w;
      }
    }
    s16x8 bB[5], qf[4];
#pragma unroll
    for (int jo = 0; jo < 5; ++jo)
      bB[jo] = *(const s16x8*)(Bb + (long)(jo * 16 + l15) * MFEAT + c * 32 + lk * 8);
#pragma unroll
    for (int i = 0; i < 4; ++i)
      qf[i] = *(const s16x8*)(qTw + (i * 16 + l15) * 40 + lk * 8);
    __builtin_amdgcn_s_setprio(1);
#pragma unroll
    for (int jo = 0; jo < 5; ++jo)
#pragma unroll
      for (int i = 0; i < 4; ++i) oacc[jo][i] = MFMA(bB[jo], qf[i], oacc[jo][i]);
    __builtin_amdgcn_s_setprio(0);
  }
  // analytic eps term with lambda correction (exact)
  float lamv[4];
#pragma unroll
  for (int i = 0; i < 4; ++i) lamv[i] = __expf((tm[i] - rm[i]) * NORMALIZER);
#pragma unroll
  for (int jo = 0; jo < 5; ++jo) {
    f4v bs = *(const f4v*)(bsum + (long)bh * 80 + jo * 16 + lk * 4);
#pragma unroll
    for (int i = 0; i < 4; ++i)
#pragma unroll
      for (int r = 0; r < 4; ++r) oacc[jo][i][r] += (RATIO_ * EPS_) * bs[r] * lamv[i];
  }
  // epilogue: divide by denominator, stage, write
  u16* stw = qTw;  // stride 72 now
#pragma unroll
  for (int i = 0; i < 4; ++i) {
    float dn = __shfl(oacc[4][i][0], l15);  // token 16i+l15's denom from lane (l15, lk=0)
    float inv = 1.0f / dn;
#pragma unroll
    for (int jo = 0; jo < 4; ++jo) {
      us4 w;
#pragma unroll
      for (int r = 0; r < 4; ++r) w[r] = f2bf(oacc[jo][i][r] * inv);
      *(us4*)(stw + (i * 16 + l15) * 72 + jo * 16 + lk * 4) = w;
    }
  }
  u16* dst = attn + ((long)b * NTOK + tb) * CDIM + h * DHEAD;
  st_write64(stw, dst, CDIM, lane);
}

// ---------------- K6: out = attn @ w_proj^T + b_proj (BK=64, XCD-concentrated, fp32 out) ----------------
__global__ __launch_bounds__(256) void k6_proj(const u16* __restrict__ A, const u16* __restrict__ Bm,
                                               const float* __restrict__ bproj, float* __restrict__ out) {
  __shared__ u16 smem[16384];  // lA[0,8192) lB[8192,16384)
  u16* lA = smem;
  u16* lB = smem + 8192;
  int tid = threadIdx.x, lane = tid & 63, wid = tid >> 6;
  // XCD-concentration remap (bijective on [0,1536))
  int p = blockIdx.x + blockIdx.y * 6;
  int r8 = p & 7, q = p >> 3;        // q in [0,192)
  int bx = q % 6;
  int by = (q / 6) * 8 + r8;
  int m0 = by << 7, n0 = bx << 7;
  int wr = (wid >> 1) << 6, wc = (wid & 1) << 6;
  int l15 = lane & 15, lk = lane >> 4;
  int lr = lane >> 3;
  int lu = (lane & 7) ^ lr;
  const u16* Ab = A + (long)m0 * CDIM;
  const u16* Bb = Bm + (long)n0 * CDIM;
  const u16* gA = Ab + (long)(wid * 32 + lr) * CDIM + lu * 8;
  const u16* gB = Bb + (long)(wid * 32 + lr) * CDIM + lu * 8;
  u16* dA = lA + wid * 2048;
  u16* dB = lB + wid * 2048;
  f32x4 acc[4][4];
#pragma unroll
  for (int i = 0; i < 4; ++i)
#pragma unroll
    for (int j = 0; j < 4; ++j) acc[i][j] = (f32x4){0.f, 0.f, 0.f, 0.f};
  for (int k0 = 0; k0 < CDIM; k0 += 64) {
    __syncthreads();
#pragma unroll
    for (int g = 0; g < 4; ++g) {
      glds16(gA + k0 + (long)g * 8 * CDIM, dA + g * 512);
      glds16(gB + k0 + (long)g * 8 * CDIM, dB + g * 512);
    }
    __syncthreads();
#pragma unroll
    for (int ks = 0; ks < 2; ++ks) {
      s16x8 af[4], bv[4];
#pragma unroll
      for (int i = 0; i < 4; ++i) {
        int co = ((ks * 4 + lk) ^ (l15 & 7)) * 8;
        af[i] = *(const s16x8*)(lA + (wr + i * 16 + l15) * 64 + co);
        bv[i] = *(const s16x8*)(lB + (wc + i * 16 + l15) * 64 + co);
      }
#pragma unroll
      for (int i = 0; i < 4; ++i)
#pragma unroll
        for (int j = 0; j < 4; ++j) acc[i][j] = MFMA(af[i], bv[j], acc[i][j]);
    }
  }
  float bpv[4];
#pragma unroll
  for (int j = 0; j < 4; ++j) bpv[j] = bproj[n0 + wc + j * 16 + l15];
#pragma unroll
  for (int i = 0; i < 4; ++i)
#pragma unroll
    for (int j = 0; j < 4; ++j)
#pragma unroll
      for (int r = 0; r < 4; ++r) {
        long row = m0 + wr + i * 16 + lk * 4 + r;
        int col = n0 + wc + j * 16 + l15;
        out[row * CDIM + col] = acc[i][j][r] + bpv[j];
      }
}

extern "C" void kernel_launch(void* const* d_in, const int* in_sizes, int n_in,
                              void* d_out, int out_size, void* d_ws, size_t ws_size,
                              hipStream_t stream) {
  const float* x = (const float*)d_in[0];
  const float* w_qkv = (const float*)d_in[1];
  const float* w_proj = (const float*)d_in[2];
  const float* b_proj = (const float*)d_in[3];
  const float* proj = (const float*)d_in[4];
  float* out = (float*)d_out;

  char* p = (char*)d_ws;
  auto take = [&](size_t bytes) {
    char* r = p;
    p += (bytes + 255) & ~(size_t)255;
    return r;
  };
  u16* xb = (u16*)take(32768UL * 768 * 2);      // 50.33 MB; dead after k0 -> ctx8
  u16* wqkvb = (u16*)take(2304UL * 768 * 2);
  u16* wprojb = (u16*)take(768UL * 768 * 2);
  u16* projb = (u16*)take(256UL * 64 * 2);
  u16* qb = (u16*)take(96UL * 4096 * 64 * 2);   // 50.33 MB
  u16* kb = (u16*)take(96UL * 4096 * 64 * 2);   // 50.33 MB; dead after k3f -> attn
  u16* vT = (u16*)take(96UL * 64 * 4096 * 2);   // 50.33 MB
  float* kpart = (float*)take(96UL * 8 * 256 * 4);
  u16* baug = (u16*)take(96UL * 80 * 256 * 2);
  float* bsum = (float*)take(96UL * 80 * 4);
  float* tmbuf = (float*)take(96UL * 32 * 4);
  float* rmbuf = (float*)take(96UL * 32 * 4);
  float* vsumb = (float*)take(96UL * 8 * 64 * 4);
  // stream-ordered aliases
  float* ctx8 = (float*)xb;  // [8][96][64][256] f32 == 50.33 MB exactly
  u16* attn = kb;            // 50.33 MB

  cvt_all<<<26896, 256, 0, stream>>>(x, w_qkv, w_proj, proj, xb, wqkvb, wprojb, projb);
  k0_qkv<<<dim3(18, 256), 256, 0, stream>>>(xb, wqkvb, qb, kb, vT);
  k3f<<<dim3(8, 96), 256, 0, stream>>>(kb, vT, projb, ctx8, kpart, tmbuf, rmbuf, vsumb);
  k3b<<<dim3(96, 5), 256, 0, stream>>>(ctx8, kpart, tmbuf, rmbuf, vsumb, baug, bsum);
  k2q5<<<dim3(16, 96), 256, 0, stream>>>(qb, projb, baug, bsum, attn);
  k6_proj<<<dim3(6, 256), 256, 0, stream>>>(attn, wprojb, b_proj, out);
}

// Round 15
// 407.243 us; speedup vs baseline: 1.4924x; 1.0205x over previous
//
#include <hip/hip_runtime.h>
#include <hip/hip_bf16.h>

typedef __attribute__((ext_vector_type(4))) float f32x4;
typedef __attribute__((ext_vector_type(8))) short s16x8;
typedef __attribute__((ext_vector_type(4))) float f4v;
typedef __attribute__((ext_vector_type(4))) unsigned short us4;
typedef unsigned short u16;
typedef unsigned int u32;

#define H_ 12
#define NTOK 4096
#define DHEAD 64
#define MFEAT 256
#define CDIM 768

#define NORMALIZER 0.35355339059327373f  /* 64^-0.25 */
#define SCALE_QK 0.5100660791f           /* NORMALIZER * log2(e) — q/k stored pre-scaled */
#define DIAG2 0.3465735903f              /* 0.5 / log2(e): ss(scaled) -> diag*log2e */
#define RATIO_ 0.0625f                   /* 256^-0.5 = 2^-4 */
#define EPS_ 1e-4f
#define DEFER2 5.7707802f                /* 4.0 * log2(e), defer-max threshold in exp2 units */

#define MFMA(a, b, c) __builtin_amdgcn_mfma_f32_16x16x32_bf16((a), (b), (c), 0, 0, 0)

#if __has_builtin(__builtin_amdgcn_exp2f)
#define EX2(x) __builtin_amdgcn_exp2f(x)
#else
#define EX2(x) __expf((x) * 0.6931471806f)
#endif

__device__ __forceinline__ float bf2f(u16 u) {
  union { float f; u32 v; } x; x.v = ((u32)u) << 16; return x.f;
}
__device__ __forceinline__ u16 f2bf(float f) {
  union { float f; u32 v; } x; x.f = f;
  u32 v = x.v + 0x7FFFu + ((x.v >> 16) & 1u);
  return (u16)(v >> 16);
}
__device__ __forceinline__ void glds16(const u16* g, u16* l) {
  __builtin_amdgcn_global_load_lds((const __attribute__((address_space(1))) void*)g,
                                   (__attribute__((address_space(3))) void*)l, 16, 0, 0);
}

// write a wave's staged 64x64 bf16 tile (rows padded to 72) to dst
__device__ __forceinline__ void st_write64(const u16* stw, u16* dst, long ld, int lane) {
  int r0 = lane >> 3, cc = lane & 7;
#pragma unroll
  for (int c = 0; c < 8; ++c) {
    int row = c * 8 + r0;
    s16x8 v = *(const s16x8*)(stw + row * 72 + cc * 8);
    *(s16x8*)(dst + (long)row * ld + cc * 8) = v;
  }
}

// ---------------- fused fp32->bf16 converts (block-aligned segments) ----------------
__global__ void cvt_all(const float* __restrict__ x, const float* __restrict__ wq,
                        const float* __restrict__ wp, const float* __restrict__ pj,
                        u16* __restrict__ xb, u16* __restrict__ wqb,
                        u16* __restrict__ wpb, u16* __restrict__ pjb) {
  int b = blockIdx.x;
  const float* s;
  u16* d;
  int base;
  if (b < 24576)      { s = x;  d = xb;  base = b; }
  else if (b < 26304) { s = wq; d = wqb; base = b - 24576; }
  else if (b < 26880) { s = wp; d = wpb; base = b - 26304; }
  else                { s = pj; d = pjb; base = b - 26880; }
  long i = (long)base * 256 + threadIdx.x;
  f4v v = *(const f4v*)(s + i * 4);
  us4 o;
#pragma unroll
  for (int j = 0; j < 4; ++j) o[j] = f2bf(v[j]);
  *(us4*)(d + i * 4) = o;
}

// ---------------- K0: QKV GEMM, BK=64 glds16, XCD-concentrated; q/k stored PRE-SCALED by SCALE_QK ----------------
__global__ __launch_bounds__(256) void k0_qkv(const u16* __restrict__ A, const u16* __restrict__ Bm,
                                              u16* __restrict__ qb, u16* __restrict__ kb,
                                              u16* __restrict__ vT) {
  __shared__ u16 smem[4 * 64 * 72];   // loop: lA[0,8192) lB[8192,16384) u16; epilogue: 4x 64x72
  u16* lA = smem;
  u16* lB = smem + 8192;
  int tid = threadIdx.x, lane = tid & 63, wid = tid >> 6;
  // XCD-concentration remap (bijective on [0,4608))
  int p = blockIdx.x + blockIdx.y * 18;
  int r8 = p & 7, q = p >> 3;        // q in [0,576)
  int bx = q % 18;                   // N-panel member
  int by = (q / 18) * 8 + r8;        // M-panel group (same XCD for all 18 members)
  int m0 = by << 7, n0 = bx << 7;
  int wr = (wid >> 1) << 6, wc = (wid & 1) << 6;
  int l15 = lane & 15, lk = lane >> 4;
  int lr = lane >> 3;            // row within 8-row group
  int lu = (lane & 7) ^ lr;      // pre-swizzled source 16B-unit
  const u16* Ab = A + (long)m0 * CDIM;
  const u16* Bb = Bm + (long)n0 * CDIM;
  const u16* gA = Ab + (long)(wid * 32 + lr) * CDIM + lu * 8;
  const u16* gB = Bb + (long)(wid * 32 + lr) * CDIM + lu * 8;
  u16* dA = lA + wid * 2048;
  u16* dB = lB + wid * 2048;
  f32x4 acc[4][4];
#pragma unroll
  for (int i = 0; i < 4; ++i)
#pragma unroll
    for (int j = 0; j < 4; ++j) acc[i][j] = (f32x4){0.f, 0.f, 0.f, 0.f};
  for (int k0 = 0; k0 < CDIM; k0 += 64) {
    __syncthreads();
#pragma unroll
    for (int g = 0; g < 4; ++g) {
      glds16(gA + k0 + (long)g * 8 * CDIM, dA + g * 512);
      glds16(gB + k0 + (long)g * 8 * CDIM, dB + g * 512);
    }
    __syncthreads();
#pragma unroll
    for (int ks = 0; ks < 2; ++ks) {
      s16x8 af[4], bv[4];
#pragma unroll
      for (int i = 0; i < 4; ++i) {
        int co = ((ks * 4 + lk) ^ (l15 & 7)) * 8;   // swizzled read unit
        af[i] = *(const s16x8*)(lA + (wr + i * 16 + l15) * 64 + co);
        bv[i] = *(const s16x8*)(lB + (wc + i * 16 + l15) * 64 + co);
      }
#pragma unroll
      for (int i = 0; i < 4; ++i)
#pragma unroll
        for (int j = 0; j < 4; ++j) acc[i][j] = MFMA(af[i], bv[j], acc[i][j]);
    }
  }
  __syncthreads();  // before reusing smem as epilogue stage
  int colbase = n0 + wc;
  int qi = colbase / CDIM;
  int h = (colbase % CDIM) >> 6;
  int rowbase = m0 + wr;
  int b = rowbase >> 12;
  int nloc = rowbase & (NTOK - 1);
  u16* stw = smem + wid * 4608;
  if (qi < 2) {
#pragma unroll
    for (int i = 0; i < 4; ++i)
#pragma unroll
      for (int j = 0; j < 4; ++j)
#pragma unroll
        for (int r = 0; r < 4; ++r)
          stw[(i * 16 + lk * 4 + r) * 72 + j * 16 + l15] = f2bf(acc[i][j][r] * SCALE_QK);
    u16* dst = (qi == 0 ? qb : kb) + ((long)(b * H_ + h) * NTOK + nloc) * DHEAD;
    st_write64(stw, dst, DHEAD, lane);
  } else {
    // transposed stage: st[dd][n] (pack 4 r's into one b64)
#pragma unroll
    for (int i = 0; i < 4; ++i)
#pragma unroll
      for (int j = 0; j < 4; ++j) {
        us4 w;
#pragma unroll
        for (int r = 0; r < 4; ++r) w[r] = f2bf(acc[i][j][r]);
        *(us4*)(stw + (j * 16 + l15) * 72 + i * 16 + lk * 4) = w;
      }
    u16* dst = vT + (long)(b * H_ + h) * DHEAD * NTOK + nloc;
    st_write64(stw, dst, NTOK, lane);
  }
}

// ---------------- K3f: phi(k)+context, local deferred max, all exponents in exp2 units ----------------
__global__ __launch_bounds__(256) void k3f(const u16* __restrict__ kb, const u16* __restrict__ vT,
                                           const u16* __restrict__ projb,
                                           float* __restrict__ ctx8, float* __restrict__ kpart,
                                           float* __restrict__ tmbuf, float* __restrict__ rmbuf,
                                           float* __restrict__ vsumb) {
  __shared__ u16 smem[4 * 64 * 72];
  int bh = blockIdx.y, nc = blockIdx.x;  // nc in [0,8)
  int tid = threadIdx.x, lane = tid & 63, wid = tid >> 6;
  int l15 = lane & 15, lk = lane >> 4;
  int wc = wid << 6;
  const u16* Kb = kb + ((long)bh * NTOK + nc * 512) * DHEAD;
  const u16* Vb = vT + (long)bh * DHEAD * NTOK + nc * 512;
  u16* ktw = smem + wid * 4608;  // per-wave 9216B tile (wave-local!)
  f32x4 ctxa[4][4];
#pragma unroll
  for (int i = 0; i < 4; ++i)
#pragma unroll
    for (int j = 0; j < 4; ++j) ctxa[i][j] = (f32x4){0.f, 0.f, 0.f, 0.f};
  float cs[4] = {0.f, 0.f, 0.f, 0.f};
  float rm = -3.4e38f, tm = -3.4e38f;   // exp2 units
  float vsacc[4] = {0.f, 0.f, 0.f, 0.f};  // wave 0 only
  for (int sb = 0; sb < 8; ++sb) {
    const u16* Ksb = Kb + sb * 64 * DHEAD;
    s16x8 a[4][2];
    float ss[4] = {0.f, 0.f, 0.f, 0.f};
#pragma unroll
    for (int i = 0; i < 4; ++i)
#pragma unroll
      for (int ks = 0; ks < 2; ++ks) {
        a[i][ks] = *(const s16x8*)(Ksb + (long)(i * 16 + l15) * DHEAD + ks * 32 + lk * 8);
#pragma unroll
        for (int e = 0; e < 8; ++e) { float f = bf2f((u16)a[i][ks][e]); ss[i] += f * f; }
      }
    float dgv[4];
#pragma unroll
    for (int i = 0; i < 4; ++i) {
      float s = ss[i];
      s += __shfl_xor(s, 16);
      s += __shfl_xor(s, 32);
      dgv[i] = s * DIAG2;  // diag*log2e of token 16i+l15
    }
    f32x4 dacc[4][4];
#pragma unroll
    for (int i = 0; i < 4; ++i)
#pragma unroll
      for (int j = 0; j < 4; ++j) dacc[i][j] = (f32x4){0.f, 0.f, 0.f, 0.f};
    __builtin_amdgcn_s_setprio(1);
#pragma unroll
    for (int ks = 0; ks < 2; ++ks)
#pragma unroll
      for (int j = 0; j < 4; ++j) {
        s16x8 pb = *(const s16x8*)(projb + (long)(wc + j * 16 + l15) * DHEAD + ks * 32 + lk * 8);
#pragma unroll
        for (int i = 0; i < 4; ++i) dacc[i][j] = MFMA(a[i][ks], pb, dacc[i][j]);
      }
    __builtin_amdgcn_s_setprio(0);
    // wave max of scaled dash
    float cm = -3.4e38f;
#pragma unroll
    for (int i = 0; i < 4; ++i)
#pragma unroll
      for (int j = 0; j < 4; ++j)
#pragma unroll
        for (int r = 0; r < 4; ++r) cm = fmaxf(cm, dacc[i][j][r]);
    cm = fmaxf(cm, __shfl_xor(cm, 1));
    cm = fmaxf(cm, __shfl_xor(cm, 2));
    cm = fmaxf(cm, __shfl_xor(cm, 4));
    cm = fmaxf(cm, __shfl_xor(cm, 8));
    cm = fmaxf(cm, __shfl_xor(cm, 16));
    cm = fmaxf(cm, __shfl_xor(cm, 32));
    tm = fmaxf(tm, cm);
    if (cm - rm > DEFER2) {  // wave-uniform
      float fsc = EX2(rm - cm);  // 0 on first trigger (rm=-inf), accs are 0
#pragma unroll
      for (int ii = 0; ii < 4; ++ii)
#pragma unroll
        for (int jv = 0; jv < 4; ++jv) ctxa[ii][jv] *= fsc;
#pragma unroll
      for (int j = 0; j < 4; ++j) cs[j] *= fsc;
      rm = cm;
    }
    // diag at token 16i+4lk+r via shuffle
    float dgr[4][4];
#pragma unroll
    for (int i = 0; i < 4; ++i)
#pragma unroll
      for (int r = 0; r < 4; ++r) dgr[i][r] = __shfl(dgv[i], 4 * lk + r) + rm;
    // E -> kT (wave-local), packed b64 writes; E <= 2^DEFER2
#pragma unroll
    for (int i = 0; i < 4; ++i)
#pragma unroll
      for (int j = 0; j < 4; ++j) {
        us4 w;
#pragma unroll
        for (int r = 0; r < 4; ++r) {
          float v = EX2(dacc[i][j][r] - dgr[i][r]);
          cs[j] += v;
          w[r] = f2bf(v);
        }
        *(us4*)(ktw + (j * 16 + l15) * 72 + i * 16 + lk * 4) = w;
      }
    // context MFMA: A = E(features) rows from ktw, B = vT rows; + vsum on wave 0
    __builtin_amdgcn_s_setprio(1);
#pragma unroll
    for (int ks = 0; ks < 2; ++ks) {
      s16x8 a2f[4], vb[4];
#pragma unroll
      for (int ii = 0; ii < 4; ++ii)
        a2f[ii] = *(const s16x8*)(ktw + (ii * 16 + l15) * 72 + ks * 32 + lk * 8);
#pragma unroll
      for (int jv = 0; jv < 4; ++jv)
        vb[jv] = *(const s16x8*)(Vb + (long)(jv * 16 + l15) * NTOK + sb * 64 + ks * 32 + lk * 8);
      if (wid == 0) {
#pragma unroll
        for (int jv = 0; jv < 4; ++jv)
#pragma unroll
          for (int e = 0; e < 8; ++e) vsacc[jv] += bf2f((u16)vb[jv][e]);
      }
#pragma unroll
      for (int ii = 0; ii < 4; ++ii)
#pragma unroll
        for (int jv = 0; jv < 4; ++jv) ctxa[ii][jv] = MFMA(a2f[ii], vb[jv], ctxa[ii][jv]);
    }
    __builtin_amdgcn_s_setprio(0);
  }
  asm volatile("" ::: "memory");  // fence u16/f32 LDS type-pun reordering
  // epilogue: transpose wave quadrant to [dd][m] via LDS (stride 68 f32), coalesced f32 writes
  float* lf = (float*)ktw;  // 32 x 68 f32 = 8704B <= 9216B
  float* dstb = ctx8 + (long)(nc * 96 + bh) * (MFEAT * DHEAD);
#pragma unroll
  for (int half = 0; half < 2; ++half) {
#pragma unroll
    for (int jh = 0; jh < 2; ++jh) {
      int jv = half * 2 + jh;
#pragma unroll
      for (int ii = 0; ii < 4; ++ii)
        *(f4v*)(lf + (jh * 16 + l15) * 68 + ii * 16 + lk * 4) =
            (f4v){ctxa[ii][jv][0], ctxa[ii][jv][1], ctxa[ii][jv][2], ctxa[ii][jv][3]};
    }
#pragma unroll
    for (int u = 0; u < 8; ++u) {
      int dd_l = u * 4 + lk;
      f4v v = *(const f4v*)(lf + dd_l * 68 + l15 * 4);
      *(f4v*)(dstb + (long)(half * 32 + dd_l) * MFEAT + wc + l15 * 4) = v;
    }
    asm volatile("" ::: "memory");
  }
#pragma unroll
  for (int j = 0; j < 4; ++j) {
    float s = cs[j];
    s += __shfl_xor(s, 16);
    s += __shfl_xor(s, 32);
    if (lk == 0) kpart[((long)bh * 8 + nc) * MFEAT + wc + j * 16 + l15] = s;
  }
  if (lane == 0) {
    tmbuf[bh * 32 + nc * 4 + wid] = tm;
    rmbuf[bh * 32 + nc * 4 + wid] = rm;
  }
  if (wid == 0) {
#pragma unroll
    for (int jv = 0; jv < 4; ++jv) {
      float s = vsacc[jv];
      s += __shfl_xor(s, 16);
      s += __shfl_xor(s, 32);
      if (lk == 0) vsumb[((long)bh * 8 + nc) * 64 + jv * 16 + l15] = s;
    }
  }
}

// ---------------- K3b: combine chunks with exact global max (exp2 units); Baug + bsum ----------------
__global__ __launch_bounds__(256) void k3b(const float* __restrict__ ctx8, const float* __restrict__ kpart,
                                           const float* __restrict__ tmbuf, const float* __restrict__ rmbuf,
                                           const float* __restrict__ vsumb,
                                           u16* __restrict__ baug, float* __restrict__ bsum) {
  __shared__ float red[4];
  __shared__ float mgs;
  int bh = blockIdx.x, y = blockIdx.y;
  int tid = threadIdx.x, lane = tid & 63, wid4 = tid >> 6;
  int b = bh / H_;
  float ml = -3.4e38f;
  for (int i = tid; i < 384; i += 256) ml = fmaxf(ml, tmbuf[b * 384 + i]);
  ml = fmaxf(ml, __shfl_xor(ml, 1));
  ml = fmaxf(ml, __shfl_xor(ml, 2));
  ml = fmaxf(ml, __shfl_xor(ml, 4));
  ml = fmaxf(ml, __shfl_xor(ml, 8));
  ml = fmaxf(ml, __shfl_xor(ml, 16));
  ml = fmaxf(ml, __shfl_xor(ml, 32));
  if (lane == 0) red[wid4] = ml;
  __syncthreads();
  if (tid == 0) mgs = fmaxf(fmaxf(red[0], red[1]), fmaxf(red[2], red[3]));
  __syncthreads();
  float mg = mgs;
  u16* o = baug + (long)bh * 80 * MFEAT;
  if (y < 4) {
    int dd = y * 16 + (tid >> 4);
    int m0 = (tid & 15) * 16;
    int qd = m0 >> 6;
    float scale[8];
#pragma unroll
    for (int c = 0; c < 8; ++c)
      scale[c] = EX2(rmbuf[bh * 32 + c * 4 + qd] - mg);
    f4v s[4];
#pragma unroll
    for (int e = 0; e < 4; ++e) s[e] = (f4v){0.f, 0.f, 0.f, 0.f};
    for (int c = 0; c < 8; ++c) {
      const float* r = ctx8 + (long)(c * 96 + bh) * (MFEAT * DHEAD) + dd * MFEAT + m0;
#pragma unroll
      for (int e = 0; e < 4; ++e) s[e] += scale[c] * (*(const f4v*)(r + e * 4));
    }
    float vs = 0.f;
#pragma unroll
    for (int c = 0; c < 8; ++c) vs += vsumb[((long)bh * 8 + c) * 64 + dd];
    float epsb = RATIO_ * EPS_ * vs;
    float t = 0.f;
#pragma unroll
    for (int e = 0; e < 4; ++e) {
      us4 w;
#pragma unroll
      for (int q = 0; q < 4; ++q) {
        float val = RATIO_ * s[e][q] + epsb;
        t += val;
        w[q] = f2bf(val);
      }
      *(us4*)(o + dd * MFEAT + m0 + e * 4) = w;
    }
    t += __shfl_xor(t, 1); t += __shfl_xor(t, 2); t += __shfl_xor(t, 4); t += __shfl_xor(t, 8);
    if ((tid & 15) == 0) bsum[bh * 80 + dd] = t;
  } else {
    int m = tid;
    int qd = m >> 6;
    float ks = 0.f;
#pragma unroll
    for (int c = 0; c < 8; ++c)
      ks += EX2(rmbuf[bh * 32 + c * 4 + qd] - mg) * kpart[((long)bh * 8 + c) * MFEAT + m];
    ks = RATIO_ * ks + RATIO_ * EPS_ * 4096.0f;
    o[64 * MFEAT + m] = f2bf(ks);
    float t = ks;
    t += __shfl_xor(t, 1); t += __shfl_xor(t, 2); t += __shfl_xor(t, 4);
    t += __shfl_xor(t, 8); t += __shfl_xor(t, 16); t += __shfl_xor(t, 32);
    if ((m & 63) == 0) red[m >> 6] = t;
    __syncthreads();
    if (m == 0) bsum[bh * 80 + 64] = red[0] + red[1] + red[2] + red[3];
    for (int dd = 65; dd < 80; ++dd) o[dd * MFEAT + m] = 0;
    if (m < 15) bsum[bh * 80 + 65 + m] = 0.f;
  }
}

// ---------------- K2Q5: fused phi(q) + (q' @ Baug^T), defer-max, exp2 units, analytic eps ----------------
__global__ __launch_bounds__(256) void k2q5(const u16* __restrict__ qb, const u16* __restrict__ projb,
                                            const u16* __restrict__ baug, const float* __restrict__ bsum,
                                            u16* __restrict__ attn) {
  __shared__ u16 smem[4 * 64 * 72];
  int bh = blockIdx.y;
  int b = bh / H_, h = bh % H_;
  int tid = threadIdx.x, lane = tid & 63, wid = tid >> 6;
  int l15 = lane & 15, lk = lane >> 4;
  int tb = blockIdx.x * 256 + wid * 64;  // wave's 64 tokens
  const u16* Aq = qb + ((long)bh * NTOK + tb) * DHEAD;
  const u16* Bb = baug + (long)bh * 80 * MFEAT;
  u16* qTw = smem + wid * 4608;  // loop: [64 tok][40]; epilogue: [64][72]

  // resident q fragments (pre-scaled) + diag (token = 16i+l15)
  s16x8 a2[4][2];
  float ssv[4] = {0.f, 0.f, 0.f, 0.f};
#pragma unroll
  for (int i = 0; i < 4; ++i)
#pragma unroll
    for (int ks = 0; ks < 2; ++ks) {
      a2[i][ks] = *(const s16x8*)(Aq + (long)(i * 16 + l15) * DHEAD + ks * 32 + lk * 8);
#pragma unroll
      for (int e = 0; e < 8; ++e) { float f = bf2f((u16)a2[i][ks][e]); ssv[i] += f * f; }
    }
  float dgv[4];
#pragma unroll
  for (int i = 0; i < 4; ++i) {
    float s = ssv[i];
    s += __shfl_xor(s, 16);
    s += __shfl_xor(s, 32);
    dgv[i] = s * DIAG2;
  }
  float rm[4] = {-3.4e38f, -3.4e38f, -3.4e38f, -3.4e38f};  // exp2 units
  float tm[4] = {-3.4e38f, -3.4e38f, -3.4e38f, -3.4e38f};
  f32x4 oacc[5][4];
#pragma unroll
  for (int jo = 0; jo < 5; ++jo)
#pragma unroll
    for (int i = 0; i < 4; ++i) oacc[jo][i] = (f32x4){0.f, 0.f, 0.f, 0.f};

  for (int c = 0; c < 8; ++c) {  // 32-feature chunks
    s16x8 pb[2][2];
#pragma unroll
    for (int j = 0; j < 2; ++j)
#pragma unroll
      for (int ks = 0; ks < 2; ++ks)
        pb[j][ks] = *(const s16x8*)(projb + (long)(c * 32 + j * 16 + l15) * DHEAD + ks * 32 + lk * 8);
    f32x4 dacc[2][4];
#pragma unroll
    for (int j = 0; j < 2; ++j)
#pragma unroll
      for (int i = 0; i < 4; ++i) dacc[j][i] = (f32x4){0.f, 0.f, 0.f, 0.f};
    __builtin_amdgcn_s_setprio(1);
#pragma unroll
    for (int ks = 0; ks < 2; ++ks)
#pragma unroll
      for (int j = 0; j < 2; ++j)
#pragma unroll
        for (int i = 0; i < 4; ++i) dacc[j][i] = MFMA(pb[j][ks], a2[i][ks], dacc[j][i]);
    __builtin_amdgcn_s_setprio(0);
#pragma unroll
    for (int i = 0; i < 4; ++i) {
      float cm = dacc[0][i][0];
      cm = fmaxf(cm, dacc[0][i][1]); cm = fmaxf(cm, dacc[0][i][2]); cm = fmaxf(cm, dacc[0][i][3]);
      cm = fmaxf(cm, dacc[1][i][0]); cm = fmaxf(cm, dacc[1][i][1]);
      cm = fmaxf(cm, dacc[1][i][2]); cm = fmaxf(cm, dacc[1][i][3]);
      cm = fmaxf(cm, __shfl_xor(cm, 16));
      cm = fmaxf(cm, __shfl_xor(cm, 32));
      tm[i] = fmaxf(tm[i], cm);
      if (__any(cm - rm[i] > DEFER2)) {
        float rn = fmaxf(rm[i], cm);
        float fsc = EX2(rm[i] - rn);
#pragma unroll
        for (int jo = 0; jo < 5; ++jo) oacc[jo][i] *= fsc;
        rm[i] = rn;
      }
    }
    // phi = 2^(dacc - diag*log2e - rm - 4)  (RATIO=2^-4 folded) -> wave-local LDS [64 tok][40]
#pragma unroll
    for (int i = 0; i < 4; ++i) {
      float dm = dgv[i] + rm[i] + 4.0f;
#pragma unroll
      for (int j = 0; j < 2; ++j) {
        us4 w;
#pragma unroll
        for (int r = 0; r < 4; ++r)
          w[r] = f2bf(EX2(dacc[j][i][r] - dm));
        *(us4*)(qTw + (i * 16 + l15) * 40 + j * 16 + lk * 4) = w;
      }
    }
    s16x8 bB[5], qf[4];
#pragma unroll
    for (int jo = 0; jo < 5; ++jo)
      bB[jo] = *(const s16x8*)(Bb + (long)(jo * 16 + l15) * MFEAT + c * 32 + lk * 8);
#pragma unroll
    for (int i = 0; i < 4; ++i)
      qf[i] = *(const s16x8*)(qTw + (i * 16 + l15) * 40 + lk * 8);
    __builtin_amdgcn_s_setprio(1);
#pragma unroll
    for (int jo = 0; jo < 5; ++jo)
#pragma unroll
      for (int i = 0; i < 4; ++i) oacc[jo][i] = MFMA(bB[jo], qf[i], oacc[jo][i]);
    __builtin_amdgcn_s_setprio(0);
  }
  // analytic eps term with lambda correction (exact)
  float lamv[4];
#pragma unroll
  for (int i = 0; i < 4; ++i) lamv[i] = EX2(tm[i] - rm[i]);
#pragma unroll
  for (int jo = 0; jo < 5; ++jo) {
    f4v bs = *(const f4v*)(bsum + (long)bh * 80 + jo * 16 + lk * 4);
#pragma unroll
    for (int i = 0; i < 4; ++i)
#pragma unroll
      for (int r = 0; r < 4; ++r) oacc[jo][i][r] += (RATIO_ * EPS_) * bs[r] * lamv[i];
  }
  // epilogue: divide by denominator, stage, write
  u16* stw = qTw;  // stride 72 now
#pragma unroll
  for (int i = 0; i < 4; ++i) {
    float dn = __shfl(oacc[4][i][0], l15);
    float inv = 1.0f / dn;
#pragma unroll
    for (int jo = 0; jo < 4; ++jo) {
      us4 w;
#pragma unroll
      for (int r = 0; r < 4; ++r) w[r] = f2bf(oacc[jo][i][r] * inv);
      *(us4*)(stw + (i * 16 + l15) * 72 + jo * 16 + lk * 4) = w;
    }
  }
  u16* dst = attn + ((long)b * NTOK + tb) * CDIM + h * DHEAD;
  st_write64(stw, dst, CDIM, lane);
}

// ---------------- K6: out = attn @ w_proj^T + b_proj (BK=64, XCD-concentrated, fp32 out) ----------------
__global__ __launch_bounds__(256) void k6_proj(const u16* __restrict__ A, const u16* __restrict__ Bm,
                                               const float* __restrict__ bproj, float* __restrict__ out) {
  __shared__ u16 smem[16384];  // lA[0,8192) lB[8192,16384)
  u16* lA = smem;
  u16* lB = smem + 8192;
  int tid = threadIdx.x, lane = tid & 63, wid = tid >> 6;
  int p = blockIdx.x + blockIdx.y * 6;
  int r8 = p & 7, q = p >> 3;        // q in [0,192)
  int bx = q % 6;
  int by = (q / 6) * 8 + r8;
  int m0 = by << 7, n0 = bx << 7;
  int wr = (wid >> 1) << 6, wc = (wid & 1) << 6;
  int l15 = lane & 15, lk = lane >> 4;
  int lr = lane >> 3;
  int lu = (lane & 7) ^ lr;
  const u16* Ab = A + (long)m0 * CDIM;
  const u16* Bb = Bm + (long)n0 * CDIM;
  const u16* gA = Ab + (long)(wid * 32 + lr) * CDIM + lu * 8;
  const u16* gB = Bb + (long)(wid * 32 + lr) * CDIM + lu * 8;
  u16* dA = lA + wid * 2048;
  u16* dB = lB + wid * 2048;
  f32x4 acc[4][4];
#pragma unroll
  for (int i = 0; i < 4; ++i)
#pragma unroll
    for (int j = 0; j < 4; ++j) acc[i][j] = (f32x4){0.f, 0.f, 0.f, 0.f};
  for (int k0 = 0; k0 < CDIM; k0 += 64) {
    __syncthreads();
#pragma unroll
    for (int g = 0; g < 4; ++g) {
      glds16(gA + k0 + (long)g * 8 * CDIM, dA + g * 512);
      glds16(gB + k0 + (long)g * 8 * CDIM, dB + g * 512);
    }
    __syncthreads();
#pragma unroll
    for (int ks = 0; ks < 2; ++ks) {
      s16x8 af[4], bv[4];
#pragma unroll
      for (int i = 0; i < 4; ++i) {
        int co = ((ks * 4 + lk) ^ (l15 & 7)) * 8;
        af[i] = *(const s16x8*)(lA + (wr + i * 16 + l15) * 64 + co);
        bv[i] = *(const s16x8*)(lB + (wc + i * 16 + l15) * 64 + co);
      }
#pragma unroll
      for (int i = 0; i < 4; ++i)
#pragma unroll
        for (int j = 0; j < 4; ++j) acc[i][j] = MFMA(af[i], bv[j], acc[i][j]);
    }
  }
  float bpv[4];
#pragma unroll
  for (int j = 0; j < 4; ++j) bpv[j] = bproj[n0 + wc + j * 16 + l15];
#pragma unroll
  for (int i = 0; i < 4; ++i)
#pragma unroll
    for (int j = 0; j < 4; ++j)
#pragma unroll
      for (int r = 0; r < 4; ++r) {
        long row = m0 + wr + i * 16 + lk * 4 + r;
        int col = n0 + wc + j * 16 + l15;
        out[row * CDIM + col] = acc[i][j][r] + bpv[j];
      }
}

extern "C" void kernel_launch(void* const* d_in, const int* in_sizes, int n_in,
                              void* d_out, int out_size, void* d_ws, size_t ws_size,
                              hipStream_t stream) {
  const float* x = (const float*)d_in[0];
  const float* w_qkv = (const float*)d_in[1];
  const float* w_proj = (const float*)d_in[2];
  const float* b_proj = (const float*)d_in[3];
  const float* proj = (const float*)d_in[4];
  float* out = (float*)d_out;

  char* p = (char*)d_ws;
  auto take = [&](size_t bytes) {
    char* r = p;
    p += (bytes + 255) & ~(size_t)255;
    return r;
  };
  u16* xb = (u16*)take(32768UL * 768 * 2);      // 50.33 MB; dead after k0 -> ctx8
  u16* wqkvb = (u16*)take(2304UL * 768 * 2);
  u16* wprojb = (u16*)take(768UL * 768 * 2);
  u16* projb = (u16*)take(256UL * 64 * 2);
  u16* qb = (u16*)take(96UL * 4096 * 64 * 2);   // 50.33 MB
  u16* kb = (u16*)take(96UL * 4096 * 64 * 2);   // 50.33 MB; dead after k3f -> attn
  u16* vT = (u16*)take(96UL * 64 * 4096 * 2);   // 50.33 MB
  float* kpart = (float*)take(96UL * 8 * 256 * 4);
  u16* baug = (u16*)take(96UL * 80 * 256 * 2);
  float* bsum = (float*)take(96UL * 80 * 4);
  float* tmbuf = (float*)take(96UL * 32 * 4);
  float* rmbuf = (float*)take(96UL * 32 * 4);
  float* vsumb = (float*)take(96UL * 8 * 64 * 4);
  // stream-ordered aliases
  float* ctx8 = (float*)xb;  // [8][96][64][256] f32 == 50.33 MB exactly
  u16* attn = kb;            // 50.33 MB

  cvt_all<<<26896, 256, 0, stream>>>(x, w_qkv, w_proj, proj, xb, wqkvb, wprojb, projb);
  k0_qkv<<<dim3(18, 256), 256, 0, stream>>>(xb, wqkvb, qb, kb, vT);
  k3f<<<dim3(8, 96), 256, 0, stream>>>(kb, vT, projb, ctx8, kpart, tmbuf, rmbuf, vsumb);
  k3b<<<dim3(96, 5), 256, 0, stream>>>(ctx8, kpart, tmbuf, rmbuf, vsumb, baug, bsum);
  k2q5<<<dim3(16, 96), 256, 0, stream>>>(qb, projb, baug, bsum, attn);
  k6_proj<<<dim3(6, 256), 256, 0, stream>>>(attn, wprojb, b_proj, out);
}